// Round 8
// baseline (393.221 us; speedup 1.0000x reference)
//
#include <hip/hip_runtime.h>
#include <stdint.h>

#define SEQ   2048
#define HID   2048
#define NH    16
#define HD    128
#define BATCH 2

typedef unsigned short u16;
typedef unsigned int   u32;
typedef __attribute__((ext_vector_type(8)))  __bf16 bf16x8;
typedef __attribute__((ext_vector_type(4)))  __bf16 bf16x4;
typedef __attribute__((ext_vector_type(4)))  float  f32x4;
typedef __attribute__((ext_vector_type(16))) float  f32x16;

__device__ __forceinline__ u16 f2bf(float f) {
  union { float f; unsigned int u; } c; c.f = f;
  unsigned int u = c.u;
  return (u16)((u + 0x7fffu + ((u >> 16) & 1u)) >> 16);   // RNE
}

// async global->LDS, 16B/lane. HW writes wave-uniform LDS base + lane*16.
__device__ __forceinline__ void async_ld16(const void* g, void* s) {
  using gptr_t = const __attribute__((address_space(1))) char*;
  using sptr_t = __attribute__((address_space(3))) char*;
  __builtin_amdgcn_global_load_lds((gptr_t)(uintptr_t)g, (sptr_t)(uintptr_t)s, 16, 0, 0);
}

#if __has_builtin(__builtin_amdgcn_permlane32_swap)
__device__ __forceinline__ void plswap(u32& a, u32& b) {
  typedef __attribute__((ext_vector_type(2))) unsigned int u32x2;
  u32x2 r = __builtin_amdgcn_permlane32_swap(a, b, false, false);
  a = r[0]; b = r[1];
}
#else
__device__ __forceinline__ void plswap(u32& a, u32& b) {
  const int hi = (threadIdx.x & 63) >> 5;
  u32 sa = (u32)__shfl_xor((int)a, 32);
  u32 sb = (u32)__shfl_xor((int)b, 32);
  u32 na = hi ? sb : a;
  u32 nb = hi ? b  : sa;
  a = na; b = nb;
}
#endif

// ---------------------------------------------------------------- fused casts + rope tables
// exact 1-D grid: [0,8192) X; [8192,24576) Wq/Wk/Wv/Wo (4096 each); [24576,24704) rope.
__global__ void __launch_bounds__(256) cast5_kernel(
    const float* __restrict__ X,  const float* __restrict__ Wq,
    const float* __restrict__ Wk, const float* __restrict__ Wv,
    const float* __restrict__ Wo,
    u16* __restrict__ Xb, u16* __restrict__ Wqb, u16* __restrict__ Wkb,
    u16* __restrict__ Wvb, u16* __restrict__ Wob,
    float* __restrict__ cosT, float* __restrict__ sinT) {
  const int id = blockIdx.x;
  const int tid = threadIdx.x;
  if (id >= 24576) {
    const int idx = (id - 24576) * 256 + tid;          // < 32768 exact
    const int s = idx >> 4, i0 = (idx & 15) * 4;
    float4 c, sn;
    float* cp = &c.x; float* sp = &sn.x;
#pragma unroll
    for (int e = 0; e < 4; ++e) {
      const float inv = exp2f(-(float)(i0 + e) * 0.20762050593045702f);  // log2(1e4)/64
      const float ang = (float)s * inv;
      cp[e] = cosf(ang); sp[e] = sinf(ang);
    }
    ((float4*)cosT)[idx] = c;
    ((float4*)sinT)[idx] = sn;
    return;
  }
  const float* in; u16* out; int idx;
  if (id < 8192) { in = X; out = Xb; idx = id * 256 + tid; }
  else {
    const int seg = (id - 8192) >> 12;                 // 0..3
    idx = ((id - 8192) & 4095) * 256 + tid;
    in  = (seg == 0) ? Wq  : (seg == 1) ? Wk  : (seg == 2) ? Wv  : Wo;
    out = (seg == 0) ? Wqb : (seg == 1) ? Wkb : (seg == 2) ? Wvb : Wob;
  }
  const float4 v = ((const float4*)in)[idx];
  union { u16 us[4]; uint2 u2; } o;
  o.us[0] = f2bf(v.x); o.us[1] = f2bf(v.y); o.us[2] = f2bf(v.z); o.us[3] = f2bf(v.w);
  ((uint2*)out)[idx] = o.u2;
}

// ---------------------------------------------------------------- 256x256 4-phase QKV GEMM
// C[m,n] = sum_k A[m,k]*W[n,k]; M=4096, N=K=2048, 3 weights via blockIdx.z.
// BM=BN=256, BK=64, 8 waves (2M x 4N), per-wave 128x64. LDS 128 KiB dbuf.
// Issue plan per tile (opposite-parity buffer): P1: A-lo(2), P2: B(4), P4: A-hi(2).
// Waits: end-P2 vmcnt(6) retires A-hi(kt); end-P4 vmcnt(2) retires A-lo+B(kt+1).
// Min slack 2 phases (~1000 cyc >= HBM ~900); max 8 outstanding.
// [R4 lesson: 16-outstanding same-parity restage REGRESSED — do not deepen.]
// acc holds C^T per frag (operand-swapped): col=m (lane&15), row=n (fq*4+r).
__global__ void __launch_bounds__(512, 2) gemm_qkv256_kernel(
    const u16* __restrict__ A,
    const u16* __restrict__ B0, const u16* __restrict__ B1, const u16* __restrict__ B2,
    u16* __restrict__ O0, u16* __restrict__ O1, u16* __restrict__ O2,
    const float* __restrict__ cosT, const float* __restrict__ sinT) {
  extern __shared__ __align__(16) char smem[];
  const int z = blockIdx.z;
  const u16* Bw = (z == 0) ? B0 : (z == 1) ? B1 : B2;
  u16* Og = (z == 0) ? O0 : (z == 1) ? O1 : O2;

  const int tid = threadIdx.x, w = tid >> 6, lane = tid & 63;
  const int wr = w >> 2, wc = w & 3;
  const int fr = lane & 15, fq = lane >> 4;
  const int m0 = blockIdx.y * 256, n0 = blockIdx.x * 256;

  const int srow = lane >> 3;
  const int sunit = (lane & 7) ^ srow;
  const u16* gA = A  + (size_t)(m0 + w * 8 + srow) * HID + sunit * 8;
  const u16* gB = Bw + (size_t)(n0 + w * 8 + srow) * HID + sunit * 8;

  f32x4 acc[8][4] = {};

  // ---- prologue: stage K-tile 0 into buf 0 (order: A-lo, B, A-hi)
  {
    char* dA = smem + w * 1024;
    char* dB = smem + 65536 + w * 1024;
    async_ld16(gA,             dA);            // A h0 lo
    async_ld16(gA + 128 * HID, dA + 16384);    // A h1 lo
    async_ld16(gB,             dB);            // B q0
    async_ld16(gB + 64 * HID,  dB + 8192);     // B q1
    async_ld16(gB + 128 * HID, dB + 16384);    // B q2
    async_ld16(gB + 192 * HID, dB + 24576);    // B q3
    async_ld16(gA + 64 * HID,  dA + 8192);     // A h0 hi
    async_ld16(gA + 192 * HID, dA + 24576);    // A h1 hi
  }
  asm volatile("s_waitcnt vmcnt(2)" ::: "memory");   // A-lo + B done; A-hi may fly
  __builtin_amdgcn_s_barrier();

  bf16x8 af[4][2], bfr[4][2];
#pragma unroll 2
  for (int kt = 0; kt < HID / 64; ++kt) {
    const int p = kt & 1, q = p ^ 1;
    const int knext = (kt < HID / 64 - 1) ? (kt + 1) * 64 : kt * 64;  // clamp tail (harmless re-stage)
    const char* pA = smem + p * 32768 + wr * 16384;
    const char* pB = smem + 65536 + p * 32768 + (wc >> 1) * 16384;
    const u16* a    = gA + knext;
    const u16* bsrc = gB + knext;
    char* dA = smem + q * 32768 + w * 1024;
    char* dB = smem + 65536 + q * 32768 + w * 1024;

    // ============ P1: ds_read A i0-3 (8) + B j0-1 (4); stage A-lo(next)
#pragma unroll
    for (int i = 0; i < 4; ++i) {
      const int rl = i * 16 + fr;
      af[i][0] = *(const bf16x8*)(pA + rl * 128 + ((fq       ^ (rl & 7)) * 16));
      af[i][1] = *(const bf16x8*)(pA + rl * 128 + (((4 + fq) ^ (rl & 7)) * 16));
    }
#pragma unroll
    for (int j = 0; j < 2; ++j) {
      const int rbl = (wc & 1) * 64 + j * 16 + fr;
      bfr[j][0] = *(const bf16x8*)(pB + rbl * 128 + ((fq       ^ (rbl & 7)) * 16));
      bfr[j][1] = *(const bf16x8*)(pB + rbl * 128 + (((4 + fq) ^ (rbl & 7)) * 16));
    }
    async_ld16(a,             dA);
    async_ld16(a + 128 * HID, dA + 16384);
    __builtin_amdgcn_s_barrier();
    asm volatile("s_waitcnt lgkmcnt(0)" ::: "memory");
    __builtin_amdgcn_sched_barrier(0);
    __builtin_amdgcn_s_setprio(1);
#pragma unroll
    for (int i = 0; i < 4; ++i)
#pragma unroll
      for (int j = 0; j < 2; ++j) {
        acc[i][j] = __builtin_amdgcn_mfma_f32_16x16x32_bf16(bfr[j][0], af[i][0], acc[i][j], 0, 0, 0);
        acc[i][j] = __builtin_amdgcn_mfma_f32_16x16x32_bf16(bfr[j][1], af[i][1], acc[i][j], 0, 0, 0);
      }
    __builtin_amdgcn_s_setprio(0);
    __builtin_amdgcn_s_barrier();

    // ============ P2: ds_read B j2-3 (4); stage ALL B(next) (4 loads)
#pragma unroll
    for (int j = 2; j < 4; ++j) {
      const int rbl = (wc & 1) * 64 + j * 16 + fr;
      bfr[j][0] = *(const bf16x8*)(pB + rbl * 128 + ((fq       ^ (rbl & 7)) * 16));
      bfr[j][1] = *(const bf16x8*)(pB + rbl * 128 + (((4 + fq) ^ (rbl & 7)) * 16));
    }
    async_ld16(bsrc,             dB);
    async_ld16(bsrc + 64 * HID,  dB + 8192);
    async_ld16(bsrc + 128 * HID, dB + 16384);
    async_ld16(bsrc + 192 * HID, dB + 24576);
    __builtin_amdgcn_s_barrier();
    asm volatile("s_waitcnt lgkmcnt(0)" ::: "memory");
    __builtin_amdgcn_sched_barrier(0);
    __builtin_amdgcn_s_setprio(1);
#pragma unroll
    for (int i = 0; i < 4; ++i)
#pragma unroll
      for (int j = 2; j < 4; ++j) {
        acc[i][j] = __builtin_amdgcn_mfma_f32_16x16x32_bf16(bfr[j][0], af[i][0], acc[i][j], 0, 0, 0);
        acc[i][j] = __builtin_amdgcn_mfma_f32_16x16x32_bf16(bfr[j][1], af[i][1], acc[i][j], 0, 0, 0);
      }
    __builtin_amdgcn_s_setprio(0);
    asm volatile("s_waitcnt vmcnt(6)" ::: "memory");   // A-hi(kt) landed (issued prev P4)
    __builtin_amdgcn_s_barrier();

    // ============ P3: ds_read A i4-7 (8, reuse af regs); no staging
#pragma unroll
    for (int i = 0; i < 4; ++i) {
      const int rl = (i + 4) * 16 + fr;
      af[i][0] = *(const bf16x8*)(pA + rl * 128 + ((fq       ^ (rl & 7)) * 16));
      af[i][1] = *(const bf16x8*)(pA + rl * 128 + (((4 + fq) ^ (rl & 7)) * 16));
    }
    __builtin_amdgcn_s_barrier();
    asm volatile("s_waitcnt lgkmcnt(0)" ::: "memory");
    __builtin_amdgcn_sched_barrier(0);
    __builtin_amdgcn_s_setprio(1);
#pragma unroll
    for (int i = 0; i < 4; ++i)
#pragma unroll
      for (int j = 0; j < 2; ++j) {
        acc[i + 4][j] = __builtin_amdgcn_mfma_f32_16x16x32_bf16(bfr[j][0], af[i][0], acc[i + 4][j], 0, 0, 0);
        acc[i + 4][j] = __builtin_amdgcn_mfma_f32_16x16x32_bf16(bfr[j][1], af[i][1], acc[i + 4][j], 0, 0, 0);
      }
    __builtin_amdgcn_s_setprio(0);
    __builtin_amdgcn_s_barrier();

    // ============ P4: stage A-hi(next); mfma i4-7 x j2-3 (all regs held)
    async_ld16(a + 64 * HID,  dA + 8192);
    async_ld16(a + 192 * HID, dA + 24576);
    __builtin_amdgcn_s_barrier();
    __builtin_amdgcn_s_setprio(1);
#pragma unroll
    for (int i = 0; i < 4; ++i)
#pragma unroll
      for (int j = 2; j < 4; ++j) {
        acc[i + 4][j] = __builtin_amdgcn_mfma_f32_16x16x32_bf16(bfr[j][0], af[i][0], acc[i + 4][j], 0, 0, 0);
        acc[i + 4][j] = __builtin_amdgcn_mfma_f32_16x16x32_bf16(bfr[j][1], af[i][1], acc[i + 4][j], 0, 0, 0);
      }
    __builtin_amdgcn_s_setprio(0);
    asm volatile("s_waitcnt vmcnt(2)" ::: "memory");   // A-lo + B of kt+1 landed
    __builtin_amdgcn_s_barrier();
  }
  asm volatile("s_waitcnt vmcnt(0)" ::: "memory");     // drain clamped tail stages
  __syncthreads();

  // ---------------- epilogue: C tile 256x256 bf16 staged in smem (pitch 512B, unit^(m&31))
  if (z < 2) {
#pragma unroll
    for (int i = 0; i < 8; ++i)
#pragma unroll
      for (int j = 0; j < 4; ++j) {
        const int m = wr * 128 + i * 16 + fr;
        const int nb = wc * 64 + j * 16 + fq * 4;
        union { bf16x4 v; uint2 u; } cv;
        cv.v = __builtin_convertvector(acc[i][j], bf16x4);
        *(uint2*)(smem + m * 512 + (((nb >> 3) ^ (m & 31)) * 16) + (nb & 7) * 2) = cv.u;
      }
    __syncthreads();
    // rope + coalesced store: 512 thr x 8 cols = 16 rows / iter
#pragma unroll
    for (int rr = 0; rr < 16; ++rr) {
      const int row = rr * 16 + (tid >> 5);
      const int nb = (tid & 31) * 8;
      const int i0 = nb & 63;
      const bf16x8 x  = *(const bf16x8*)(smem + row * 512 + (((nb >> 3) ^ (row & 31)) * 16));
      const bf16x8 xp = *(const bf16x8*)(smem + row * 512 + ((((nb ^ 64) >> 3) ^ (row & 31)) * 16));
      const int mg = m0 + row;
      const int s = mg & (SEQ - 1), b = mg >> 11;
      const float4 c0 = *(const float4*)(cosT + s * 64 + i0);
      const float4 c1 = *(const float4*)(cosT + s * 64 + i0 + 4);
      const float4 s0 = *(const float4*)(sinT + s * 64 + i0);
      const float4 s1 = *(const float4*)(sinT + s * 64 + i0 + 4);
      const float cs[8] = {c0.x, c0.y, c0.z, c0.w, c1.x, c1.y, c1.z, c1.w};
      const float sn[8] = {s0.x, s0.y, s0.z, s0.w, s1.x, s1.y, s1.z, s1.w};
      const float sgn = ((nb & 127) < 64) ? -1.f : 1.f;
      union { bf16x8 v; uint4 u; } o;
#pragma unroll
      for (int e = 0; e < 8; ++e)
        o.v[e] = (__bf16)((float)x[e] * cs[e] + sgn * (float)xp[e] * sn[e]);
      const int h = (n0 >> 7) + (nb >> 7);
      *(uint4*)(Og + (((size_t)(b * NH + h) * SEQ + s) << 7) + (nb & 127)) = o.u;
    }
  } else {
    // V: stage C^T [n=d][m=s] scalar, then coalesced Vt stores
#pragma unroll
    for (int i = 0; i < 8; ++i)
#pragma unroll
      for (int j = 0; j < 4; ++j)
#pragma unroll
        for (int r = 0; r < 4; ++r) {
          const int m = wr * 128 + i * 16 + fr;
          const int n = wc * 64 + j * 16 + fq * 4 + r;
          *(u16*)(smem + n * 512 + (((m >> 3) ^ (n & 31)) * 16) + (m & 7) * 2) = f2bf(acc[i][j][r]);
        }
    __syncthreads();
#pragma unroll
    for (int rr = 0; rr < 16; ++rr) {
      const int row = rr * 16 + (tid >> 5);     // local n (2 heads x 128 d)
      const int mb = (tid & 31) * 8;
      const uint4 v = *(const uint4*)(smem + row * 512 + (((mb >> 3) ^ (row & 31)) * 16));
      const int d = row & 127, h = (n0 >> 7) + (row >> 7);
      const int mg = m0 + mb;
      const int s = mg & (SEQ - 1), b = mg >> 11;
      *(uint4*)(Og + (((size_t)((b * NH + h) * HD + d)) << 11) + s) = v;
    }
  }
}

// ---------------------------------------------------------------- out-proj GEMM
// BM=128, BN=256, BK=64, 512 thr, per-wave 64x64. LDS 144 KiB triple-buffer.
// fp32 row-major out via LDS-staged coalesced float4 stores. Grid 8x32 = 256 blocks.
__global__ void __launch_bounds__(512, 2) gemm_out_kernel(
    const u16* __restrict__ A, const u16* __restrict__ Bw, float* __restrict__ O) {
  extern __shared__ __align__(16) char smem[];
  const int tid = threadIdx.x, w = tid >> 6, lane = tid & 63;
  const int wr = w >> 2, wc = w & 3;
  const int fr = lane & 15, fq = lane >> 4;
  const int m0 = blockIdx.y * 128, n0 = blockIdx.x * 256;

  constexpr int ABUF = 16384, BBUF = 32768;
  char* const sA0 = smem;
  char* const sB0 = smem + 3 * ABUF;

  const int srow = lane >> 3;
  const int sunit = (lane & 7) ^ srow;
  const u16* gA = A  + (size_t)(m0 + w * 8 + srow) * HID + sunit * 8;
  const u16* gB = Bw + (size_t)(n0 + w * 8 + srow) * HID + sunit * 8;

  f32x4 acc[4][4] = {};

  {
    char* dA = sA0 + w * 1024;
    char* dB = sB0 + w * 1024;
    async_ld16(gA,                 dA);
    async_ld16(gA + 64 * HID,      dA + 8192);
    async_ld16(gB,                 dB);
    async_ld16(gB + 64 * HID,      dB + 8192);
    async_ld16(gB + 128 * HID,     dB + 16384);
    async_ld16(gB + 192 * HID,     dB + 24576);
    async_ld16(gA + 64,                 dA + ABUF);
    async_ld16(gA + 64 + 64 * HID,      dA + ABUF + 8192);
    async_ld16(gB + 64,                 dB + BBUF);
    async_ld16(gB + 64 + 64 * HID,      dB + BBUF + 8192);
    async_ld16(gB + 64 + 128 * HID,     dB + BBUF + 16384);
    async_ld16(gB + 64 + 192 * HID,     dB + BBUF + 24576);
  }
  asm volatile("s_waitcnt vmcnt(6)" ::: "memory");
  __builtin_amdgcn_s_barrier();

  const char* prA = sA0;
  const char* prB = sB0;
  char* psA = sA0 + 2 * ABUF;
  char* psB = sB0 + 2 * BBUF;

  bf16x8 af[4][2], bfr[2][2];
  constexpr int NT = HID / 64;
#pragma unroll 1
  for (int kt = 0; kt < NT; ++kt) {
    const int kn = (kt + 2 < NT ? kt + 2 : NT - 1) * 64;
    const u16* a    = gA + kn;
    const u16* bsrc = gB + kn;
    char* dA = psA + w * 1024;
    char* dB = psB + w * 1024;

#pragma unroll
    for (int i = 0; i < 4; ++i) {
      const int rl = wr * 64 + i * 16 + fr;
      af[i][0] = *(const bf16x8*)(prA + rl * 128 + ((fq       ^ (rl & 7)) * 16));
      af[i][1] = *(const bf16x8*)(prA + rl * 128 + (((4 + fq) ^ (rl & 7)) * 16));
    }
#pragma unroll
    for (int j = 0; j < 2; ++j) {
      const int rb = wc * 64 + j * 16 + fr;
      bfr[j][0] = *(const bf16x8*)(prB + rb * 128 + ((fq       ^ (rb & 7)) * 16));
      bfr[j][1] = *(const bf16x8*)(prB + rb * 128 + (((4 + fq) ^ (rb & 7)) * 16));
    }
    async_ld16(a,            dA);
    async_ld16(a + 64 * HID, dA + 8192);
    async_ld16(bsrc,         dB);
    __builtin_amdgcn_s_barrier();
    asm volatile("s_waitcnt lgkmcnt(0)" ::: "memory");
    __builtin_amdgcn_sched_barrier(0);
    __builtin_amdgcn_s_setprio(1);
#pragma unroll
    for (int i = 0; i < 4; ++i)
#pragma unroll
      for (int j = 0; j < 2; ++j) {
        acc[i][j] = __builtin_amdgcn_mfma_f32_16x16x32_bf16(bfr[j][0], af[i][0], acc[i][j], 0, 0, 0);
        acc[i][j] = __builtin_amdgcn_mfma_f32_16x16x32_bf16(bfr[j][1], af[i][1], acc[i][j], 0, 0, 0);
      }
    __builtin_amdgcn_s_setprio(0);
    __builtin_amdgcn_s_barrier();

#pragma unroll
    for (int j = 0; j < 2; ++j) {
      const int rb = wc * 64 + (j + 2) * 16 + fr;
      bfr[j][0] = *(const bf16x8*)(prB + rb * 128 + ((fq       ^ (rb & 7)) * 16));
      bfr[j][1] = *(const bf16x8*)(prB + rb * 128 + (((4 + fq) ^ (rb & 7)) * 16));
    }
    async_ld16(bsrc + 64 * HID,  dB + 8192);
    async_ld16(bsrc + 128 * HID, dB + 16384);
    async_ld16(bsrc + 192 * HID, dB + 24576);
    __builtin_amdgcn_s_barrier();
    asm volatile("s_waitcnt lgkmcnt(0)" ::: "memory");
    __builtin_amdgcn_sched_barrier(0);
    __builtin_amdgcn_s_setprio(1);
#pragma unroll
    for (int i = 0; i < 4; ++i)
#pragma unroll
      for (int j = 0; j < 2; ++j) {
        acc[i][j + 2] = __builtin_amdgcn_mfma_f32_16x16x32_bf16(bfr[j][0], af[i][0], acc[i][j + 2], 0, 0, 0);
        acc[i][j + 2] = __builtin_amdgcn_mfma_f32_16x16x32_bf16(bfr[j][1], af[i][1], acc[i][j + 2], 0, 0, 0);
      }
    __builtin_amdgcn_s_setprio(0);
    asm volatile("s_waitcnt vmcnt(6)" ::: "memory");
    __builtin_amdgcn_s_barrier();

    prA += ABUF; if (prA == sA0 + 3 * ABUF) prA = sA0;
    prB += BBUF; if (prB == sB0 + 3 * BBUF) prB = sB0;
    psA += ABUF; if (psA == sA0 + 3 * ABUF) psA = sA0;
    psB += BBUF; if (psB == sB0 + 3 * BBUF) psB = sB0;
  }
  asm volatile("s_waitcnt vmcnt(0)" ::: "memory");
  __syncthreads();

  // stage fp32 C [128][256], pitch 1024B, 16B-unit swizzle ^(m&63); coalesced f32x4 stores
#pragma unroll
  for (int i = 0; i < 4; ++i)
#pragma unroll
    for (int j = 0; j < 4; ++j) {
      const int m = wr * 64 + i * 16 + fr;
      const int u = wc * 16 + j * 4 + fq;      // n/4
      *(f32x4*)(smem + m * 1024 + ((u ^ (m & 63)) * 16)) = acc[i][j];
    }
  __syncthreads();
#pragma unroll
  for (int rr = 0; rr < 16; ++rr) {
    const int row = rr * 8 + (tid >> 6);
    const int u = tid & 63;
    const f32x4 v = *(const f32x4*)(smem + row * 1024 + ((u ^ (row & 63)) * 16));
    *(f32x4*)(O + (size_t)(m0 + row) * HID + n0 + u * 4) = v;
  }
}

// ---------------------------------------------------------------- flash attention, 32x32x16 MFMA
// 4 waves x 64 q-rows (256 thr), BlockQ=256, 64 keys/kt. S^T = K*Q^T; O^T = Vt*P^T.
// KEY CHANGE vs R6: each wave owns TWO 32-q sets (A at w*64, B at w*64+32); every
// shared kf/vf LDS read feeds 2 MFMAs -> per-CU LDS read traffic HALVES (the R6
// structure was LDS-BW-bound: 8 waves x 32KB = 256KB/tile vs 32KB of data).
// VGPR ~280 -> launch_bounds(256,1). K/V dbuf (2x32KB), counted vmcnt(8),
// raw barriers, XCD-aware map, T13 defer-max per set.
__global__ void __launch_bounds__(256, 1) attn_kernel(const u16* __restrict__ Qg,
                                                      const u16* __restrict__ Kg,
                                                      const u16* __restrict__ Vtg,
                                                      u16* __restrict__ Ctx) {
  __shared__ __align__(16) char smem[65536];

  const int id = blockIdx.x;                 // 256 blocks
  const int s_ = id >> 3;                    // 0..31
  const int bh = (id & 7) + 8 * (s_ >> 3);   // 0..31
  const int qt = s_ & 7;                     // 8 q-tiles of 256 rows
  const int b = bh >> 4, h = bh & (NH - 1);
  const int tid = threadIdx.x, w = tid >> 6, lane = tid & 63;   // w 0..3
  const int ml = lane & 31, hi = lane >> 5;
  const int mlB = ml + 32;

  const u16* Kbase = Kg  + (size_t)bh * SEQ * HD;
  const u16* Vbase = Vtg + (size_t)bh * HD * SEQ;
  const u16* Qbase = Qg  + (size_t)bh * SEQ * HD;

  // ---- stage Q tile 256 x 128 (64 KB) across full smem, swizzled; 16 loads/wave
  {
    const int r4 = lane >> 4;
    const int up = lane & 15;
#pragma unroll
    for (int blk = 0; blk < 16; ++blk) {
      const int row = w * 64 + blk * 4 + r4;
      const int ul = up ^ (row & 15);
      async_ld16(Qbase + (size_t)(qt * 256 + row) * HD + ul * 8, smem + w * 16384 + blk * 1024);
    }
  }
  asm volatile("s_waitcnt vmcnt(0)" ::: "memory");
  __builtin_amdgcn_s_barrier();
  const int qrowA = w * 64 + ml;
  const int qrowB = qrowA + 32;
  bf16x8 qfA[8], qfB[8];
#pragma unroll
  for (int kc = 0; kc < 8; ++kc) {
    qfA[kc] = *(const bf16x8*)(smem + qrowA * 256 + (((kc * 2 + hi) ^ (qrowA & 15)) * 16));
    qfB[kc] = *(const bf16x8*)(smem + qrowB * 256 + (((kc * 2 + hi) ^ (qrowB & 15)) * 16));
  }
  asm volatile("s_waitcnt lgkmcnt(0)" ::: "memory");   // Q reads done before buf0 overwrite
  __builtin_amdgcn_sched_barrier(0);
  __builtin_amdgcn_s_barrier();

  const int r4 = lane >> 4, up16 = lane & 15;
  const int r8 = lane >> 3, up8 = lane & 7;

  // ---- prologue: stage kt=0 into buf0 (K at +0 [16K], V at +16384 [16K]); 8 loads/wave
  {
#pragma unroll
    for (int blk = 0; blk < 4; ++blk) {
      const int row = w * 16 + blk * 4 + r4;             // K rows 0..63
      const int ul = up16 ^ (row & 15);
      async_ld16(Kbase + (size_t)row * HD + ul * 8, smem + w * 4096 + blk * 1024);
    }
#pragma unroll
    for (int blk = 0; blk < 4; ++blk) {
      const int d = w * 32 + blk * 8 + r8;               // V d-rows 0..127
      const int ul = up8 ^ (d & 7);
      async_ld16(Vbase + (size_t)d * SEQ + ul * 8, smem + 16384 + w * 4096 + blk * 1024);
    }
  }

  f32x16 accoA[4] = {}, accoB[4] = {};
  float m_runA = -1e30f, l_runA = 0.f;
  float m_runB = -1e30f, l_runB = 0.f;
  const float scale2 = (float)(1.4426950408889634 / 11.313708498984761);  // log2(e)/sqrt(128)
  constexpr int NT = SEQ / 64;

  for (int kt = 0; kt < NT; ++kt) {
    const char* bufR = smem + (kt & 1) * 32768;
    // ledger (per wave): 8 loads/tile, in-order retire -> vmcnt(8) == tile kt landed.
    if (kt + 1 < NT) {
      char* bufS = smem + ((kt + 1) & 1) * 32768;
      const int k0 = (kt + 1) * 64;
#pragma unroll
      for (int blk = 0; blk < 4; ++blk) {
        const int row = w * 16 + blk * 4 + r4;
        const int ul = up16 ^ (row & 15);
        async_ld16(Kbase + (size_t)(k0 + row) * HD + ul * 8, bufS + w * 4096 + blk * 1024);
      }
#pragma unroll
      for (int blk = 0; blk < 4; ++blk) {
        const int d = w * 32 + blk * 8 + r8;
        const int ul = up8 ^ (d & 7);
        async_ld16(Vbase + (size_t)d * SEQ + k0 + ul * 8, bufS + 16384 + w * 4096 + blk * 1024);
      }
      asm volatile("s_waitcnt vmcnt(8)" ::: "memory");
    } else {
      asm volatile("s_waitcnt vmcnt(0)" ::: "memory");
    }
    __builtin_amdgcn_s_barrier();

    // ---- QK^T: each kf read feeds both q-sets (LDS traffic halved)
    f32x16 accsA[2] = {}, accsB[2] = {};
    __builtin_amdgcn_s_setprio(1);
#pragma unroll
    for (int t = 0; t < 2; ++t) {
      const int row = t * 32 + ml;
#pragma unroll
      for (int kc = 0; kc < 8; ++kc) {
        const bf16x8 kf = *(const bf16x8*)(bufR + row * 256 + (((kc * 2 + hi) ^ (row & 15)) * 16));
        accsA[t] = __builtin_amdgcn_mfma_f32_32x32x16_bf16(kf, qfA[kc], accsA[t], 0, 0, 0);
        accsB[t] = __builtin_amdgcn_mfma_f32_32x32x16_bf16(kf, qfB[kc], accsB[t], 0, 0, 0);
      }
    }
    __builtin_amdgcn_s_setprio(0);

    // ---- softmax set A
    accsA[0] *= scale2; accsA[1] *= scale2;
    {
      const f32x16 mm = __builtin_elementwise_max(accsA[0], accsA[1]);
      float mx = mm[0];
#pragma unroll
      for (int i = 1; i < 16; ++i) mx = fmaxf(mx, mm[i]);
      mx = fmaxf(mx, __shfl_xor(mx, 32));
      if (!__all(mx - m_runA <= 8.f)) {
        const float mnew = fmaxf(m_runA, mx);
        const float alpha = __builtin_amdgcn_exp2f(m_runA - mnew);
        m_runA = mnew;
        l_runA *= alpha;
#pragma unroll
        for (int dt = 0; dt < 4; ++dt) accoA[dt] *= alpha;
      }
      float rs = 0.f;
#pragma unroll
      for (int t = 0; t < 2; ++t)
#pragma unroll
        for (int i = 0; i < 16; ++i) {
          accsA[t][i] = __builtin_amdgcn_exp2f(accsA[t][i] - m_runA);
          rs += accsA[t][i];
        }
      rs += __shfl_xor(rs, 32);
      l_runA += rs;
    }
    // ---- softmax set B
    accsB[0] *= scale2; accsB[1] *= scale2;
    {
      const f32x16 mm = __builtin_elementwise_max(accsB[0], accsB[1]);
      float mx = mm[0];
#pragma unroll
      for (int i = 1; i < 16; ++i) mx = fmaxf(mx, mm[i]);
      mx = fmaxf(mx, __shfl_xor(mx, 32));
      if (!__all(mx - m_runB <= 8.f)) {
        const float mnew = fmaxf(m_runB, mx);
        const float alpha = __builtin_amdgcn_exp2f(m_runB - mnew);
        m_runB = mnew;
        l_runB *= alpha;
#pragma unroll
        for (int dt = 0; dt < 4; ++dt) accoB[dt] *= alpha;
      }
      float rs = 0.f;
#pragma unroll
      for (int t = 0; t < 2; ++t)
#pragma unroll
        for (int i = 0; i < 16; ++i) {
          accsB[t][i] = __builtin_amdgcn_exp2f(accsB[t][i] - m_runB);
          rs += accsB[t][i];
        }
      rs += __shfl_xor(rs, 32);
      l_runB += rs;
    }

    // ---- pack P -> bf16 fragments (both sets)
    bf16x8 pfA[4], pfB[4];
    {
      u32 pk[2][4][2];
#pragma unroll
      for (int t = 0; t < 2; ++t)
#pragma unroll
        for (int g = 0; g < 4; ++g) {
          const f32x4 gv = {accsA[t][4 * g], accsA[t][4 * g + 1], accsA[t][4 * g + 2], accsA[t][4 * g + 3]};
          union { bf16x4 v; u32 u[2]; } cv; cv.v = __builtin_convertvector(gv, bf16x4);
          pk[t][g][0] = cv.u[0]; pk[t][g][1] = cv.u[1];
        }
#pragma unroll
      for (int kc = 0; kc < 4; ++kc) {
        const int t = kc >> 1, g0 = (kc & 1) * 2;
        u32 a0 = pk[t][g0][0], a1 = pk[t][g0][1];
        u32 b0 = pk[t][g0 + 1][0], b1 = pk[t][g0 + 1][1];
        plswap(a0, b0); plswap(a1, b1);
        union { u32 u[4]; bf16x8 v; } fu;
        fu.u[0] = a0; fu.u[1] = a1; fu.u[2] = b0; fu.u[3] = b1;
        pfA[kc] = fu.v;
      }
    }
    {
      u32 pk[2][4][2];
#pragma unroll
      for (int t = 0; t < 2; ++t)
#pragma unroll
        for (int g = 0; g < 4; ++g) {
          const f32x4 gv = {accsB[t][4 * g], accsB[t][4 * g + 1], accsB[t][4 * g + 2], accsB[t][4 * g + 3]};
          union { bf16x4 v; u32 u[2]; } cv; cv.v = __builtin_convertvector(gv, bf16x4);
          pk[t][g][0] = cv.u[0]; pk[t][g][1] = cv.u[1];
        }
#pragma unroll
      for (int kc = 0; kc < 4; ++kc) {
        const int t = kc >> 1, g0 = (kc & 1) * 2;
        u32 a0 = pk[t][g0][0], a1 = pk[t][g0][1];
        u32 b0 = pk[t][g0 + 1][0], b1 = pk[t][g0 + 1][1];
        plswap(a0, b0); plswap(a1, b1);
        union { u32 u[4]; bf16x8 v; } fu;
        fu.u[0] = a0; fu.u[1] = a1; fu.u[2] = b0; fu.u[3] = b1;
        pfB[kc] = fu.v;
      }
    }

    // ---- PV: each vf read feeds both q-sets
    __builtin_amdgcn_s_setprio(1);
#pragma unroll
    for (int dt = 0; dt < 4; ++dt) {
      const int d = dt * 32 + ml;
#pragma unroll
      for (int kc = 0; kc < 4; ++kc) {
        const bf16x8 vf = *(const bf16x8*)(bufR + 16384 + d * 128 + (((kc * 2 + hi) ^ (d & 7)) * 16));
        accoA[dt] = __builtin_amdgcn_mfma_f32_32x32x16_bf16(vf, pfA[kc], accoA[dt], 0, 0, 0);
        accoB[dt] = __builtin_amdgcn_mfma_f32_32x32x16_bf16(vf, pfB[kc], accoB[dt], 0, 0, 0);
      }
    }
    __builtin_amdgcn_s_setprio(0);
    // all reads of bufR must COMPLETE before any wave's next-iter stage overwrites it
    asm volatile("s_waitcnt lgkmcnt(0)" ::: "memory");
    __builtin_amdgcn_sched_barrier(0);
    __builtin_amdgcn_s_barrier();
  }

  __syncthreads();
  char* ep = smem + w * 16384;        // 64 rows x 256B per wave
  const float rcpA = 1.f / l_runA;
  const float rcpB = 1.f / l_runB;
#pragma unroll
  for (int dt = 0; dt < 4; ++dt) {
#pragma unroll
    for (int g = 0; g < 4; ++g) {
      const int ul = dt * 4 + g;
      {
        const f32x4 gv = {accoA[dt][4 * g] * rcpA, accoA[dt][4 * g + 1] * rcpA,
                          accoA[dt][4 * g + 2] * rcpA, accoA[dt][4 * g + 3] * rcpA};
        union { bf16x4 v; uint2 u2; } cv; cv.v = __builtin_convertvector(gv, bf16x4);
        *(uint2*)(ep + ml * 256 + ((ul ^ (ml & 15)) * 16) + hi * 8) = cv.u2;
      }
      {
        const f32x4 gv = {accoB[dt][4 * g] * rcpB, accoB[dt][4 * g + 1] * rcpB,
                          accoB[dt][4 * g + 2] * rcpB, accoB[dt][4 * g + 3] * rcpB};
        union { bf16x4 v; uint2 u2; } cv; cv.v = __builtin_convertvector(gv, bf16x4);
        *(uint2*)(ep + mlB * 256 + ((ul ^ (mlB & 15)) * 16) + hi * 8) = cv.u2;
      }
    }
  }
  __syncthreads();
#pragma unroll
  for (int rr = 0; rr < 16; ++rr) {
    const int idr = rr * 64 + lane;          // 0..1023
    const int qv = idr >> 4, ul = idr & 15;  // qv 0..63
    const uint4 v = *(const uint4*)(ep + qv * 256 + ((ul ^ (qv & 15)) * 16));
    *(uint4*)(Ctx + (size_t)(b * SEQ + qt * 256 + w * 64 + qv) * HID + h * HD + ul * 8) = v;
  }
}

// ---------------------------------------------------------------- launcher
extern "C" void kernel_launch(void* const* d_in, const int* in_sizes, int n_in,
                              void* d_out, int out_size, void* d_ws, size_t ws_size,
                              hipStream_t stream) {
  (void)in_sizes; (void)n_in; (void)out_size; (void)ws_size;
  const float* X  = (const float*)d_in[0];
  const float* Wq = (const float*)d_in[1];
  const float* Wk = (const float*)d_in[2];
  const float* Wv = (const float*)d_in[3];
  const float* Wo = (const float*)d_in[4];
  float* out = (float*)d_out;
  char* ws = (char*)d_ws;
  const size_t MB = 1024 * 1024;
  u16* Xb  = (u16*)(ws + 0 * MB);
  u16* Wqb = (u16*)(ws + 16 * MB);
  u16* Wkb = (u16*)(ws + 24 * MB);
  u16* Wvb = (u16*)(ws + 32 * MB);
  u16* Wob = (u16*)(ws + 40 * MB);
  u16* Qb  = (u16*)(ws + 48 * MB);
  u16* Kb  = (u16*)(ws + 64 * MB);
  u16* Vtb = (u16*)(ws + 80 * MB);   // [B,NH,HD,S] — written directly by gemm_qkv256 z=2
  // rope tables live in the Ctx region: read only by the QKV gemm, dead before attn writes Ctx
  float* cosT = (float*)(ws + 96 * MB);
  float* sinT = cosT + SEQ * 64;
  u16* Ctx = (u16*)(ws + 96 * MB);

  static bool attr_set = false;
  if (!attr_set) {
    hipFuncSetAttribute(reinterpret_cast<const void*>(&gemm_qkv256_kernel),
                        hipFuncAttributeMaxDynamicSharedMemorySize, 131072);
    hipFuncSetAttribute(reinterpret_cast<const void*>(&gemm_out_kernel),
                        hipFuncAttributeMaxDynamicSharedMemorySize, 147456);
    attr_set = true;
  }

  cast5_kernel<<<dim3(24704), 256, 0, stream>>>(X, Wq, Wk, Wv, Wo,
                                                Xb, Wqb, Wkb, Wvb, Wob, cosT, sinT);
  gemm_qkv256_kernel<<<dim3(HID / 256, (BATCH * SEQ) / 256, 3), 512, 131072, stream>>>(
      Xb, Wqb, Wkb, Wvb, Qb, Kb, Vtb, cosT, sinT);
  // attn: 256 blocks (8 q-tiles x 32 bh) = exactly 1 block/CU, 256 thr (4 waves x 64 q)
  attn_kernel<<<dim3((SEQ / 256) * BATCH * NH), 256, 0, stream>>>(Qb, Kb, Vtb, Ctx);
  gemm_out_kernel<<<dim3(HID / 256, (BATCH * SEQ) / 128), 512, 147456, stream>>>(
      Ctx, Wob, out);
}

// Round 9
// 357.943 us; speedup vs baseline: 1.0986x; 1.0986x over previous
//
#include <hip/hip_runtime.h>
#include <stdint.h>

#define SEQ   2048
#define HID   2048
#define NH    16
#define HD    128
#define BATCH 2

typedef unsigned short u16;
typedef unsigned int   u32;
typedef __attribute__((ext_vector_type(8)))  __bf16 bf16x8;
typedef __attribute__((ext_vector_type(4)))  __bf16 bf16x4;
typedef __attribute__((ext_vector_type(4)))  float  f32x4;
typedef __attribute__((ext_vector_type(16))) float  f32x16;

__device__ __forceinline__ u16 f2bf(float f) {
  union { float f; unsigned int u; } c; c.f = f;
  unsigned int u = c.u;
  return (u16)((u + 0x7fffu + ((u >> 16) & 1u)) >> 16);   // RNE
}

// async global->LDS, 16B/lane. HW writes wave-uniform LDS base + lane*16.
__device__ __forceinline__ void async_ld16(const void* g, void* s) {
  using gptr_t = const __attribute__((address_space(1))) char*;
  using sptr_t = __attribute__((address_space(3))) char*;
  __builtin_amdgcn_global_load_lds((gptr_t)(uintptr_t)g, (sptr_t)(uintptr_t)s, 16, 0, 0);
}

#if __has_builtin(__builtin_amdgcn_permlane32_swap)
__device__ __forceinline__ void plswap(u32& a, u32& b) {
  typedef __attribute__((ext_vector_type(2))) unsigned int u32x2;
  u32x2 r = __builtin_amdgcn_permlane32_swap(a, b, false, false);
  a = r[0]; b = r[1];
}
#else
__device__ __forceinline__ void plswap(u32& a, u32& b) {
  const int hi = (threadIdx.x & 63) >> 5;
  u32 sa = (u32)__shfl_xor((int)a, 32);
  u32 sb = (u32)__shfl_xor((int)b, 32);
  u32 na = hi ? sb : a;
  u32 nb = hi ? b  : sa;
  a = na; b = nb;
}
#endif

// ---------------------------------------------------------------- fused casts + rope tables
// exact 1-D grid: [0,8192) X; [8192,24576) Wq/Wk/Wv/Wo (4096 each); [24576,24704) rope.
__global__ void __launch_bounds__(256) cast5_kernel(
    const float* __restrict__ X,  const float* __restrict__ Wq,
    const float* __restrict__ Wk, const float* __restrict__ Wv,
    const float* __restrict__ Wo,
    u16* __restrict__ Xb, u16* __restrict__ Wqb, u16* __restrict__ Wkb,
    u16* __restrict__ Wvb, u16* __restrict__ Wob,
    float* __restrict__ cosT, float* __restrict__ sinT) {
  const int id = blockIdx.x;
  const int tid = threadIdx.x;
  if (id >= 24576) {
    const int idx = (id - 24576) * 256 + tid;          // < 32768 exact
    const int s = idx >> 4, i0 = (idx & 15) * 4;
    float4 c, sn;
    float* cp = &c.x; float* sp = &sn.x;
#pragma unroll
    for (int e = 0; e < 4; ++e) {
      const float inv = exp2f(-(float)(i0 + e) * 0.20762050593045702f);  // log2(1e4)/64
      const float ang = (float)s * inv;
      cp[e] = cosf(ang); sp[e] = sinf(ang);
    }
    ((float4*)cosT)[idx] = c;
    ((float4*)sinT)[idx] = sn;
    return;
  }
  const float* in; u16* out; int idx;
  if (id < 8192) { in = X; out = Xb; idx = id * 256 + tid; }
  else {
    const int seg = (id - 8192) >> 12;                 // 0..3
    idx = ((id - 8192) & 4095) * 256 + tid;
    in  = (seg == 0) ? Wq  : (seg == 1) ? Wk  : (seg == 2) ? Wv  : Wo;
    out = (seg == 0) ? Wqb : (seg == 1) ? Wkb : (seg == 2) ? Wvb : Wob;
  }
  const float4 v = ((const float4*)in)[idx];
  union { u16 us[4]; uint2 u2; } o;
  o.us[0] = f2bf(v.x); o.us[1] = f2bf(v.y); o.us[2] = f2bf(v.z); o.us[3] = f2bf(v.w);
  ((uint2*)out)[idx] = o.u2;
}

// ---------------------------------------------------------------- 256x256 4-phase QKV GEMM (verified R1/R3/R5/R6)
// C[m,n] = sum_k A[m,k]*W[n,k]; M=4096, N=K=2048, 3 weights via blockIdx.z.
// BM=BN=256, BK=64, 8 waves (2M x 4N), per-wave 128x64. LDS 128 KiB dbuf.
// kt+1 staged into OPPOSITE-parity buffer; counted vmcnt(4)/vmcnt(2) once each
// per K-tile (never 0 in loop); max 10 loads outstanding.
// SCHEDULE IS A LOCAL OPTIMUM — do not mutate:
//  [R4: 16-outstanding same-parity kt+2 restage REGRESSED 121->155 us]
//  [R8: bunching all 4 B-loads into P2 REGRESSED 120->125.5 us]
// acc holds C^T per frag (operand-swapped): col=m (lane&15), row=n (fq*4+r).
__global__ void __launch_bounds__(512, 2) gemm_qkv256_kernel(
    const u16* __restrict__ A,
    const u16* __restrict__ B0, const u16* __restrict__ B1, const u16* __restrict__ B2,
    u16* __restrict__ O0, u16* __restrict__ O1, u16* __restrict__ O2,
    const float* __restrict__ cosT, const float* __restrict__ sinT) {
  extern __shared__ __align__(16) char smem[];
  const int z = blockIdx.z;
  const u16* Bw = (z == 0) ? B0 : (z == 1) ? B1 : B2;
  u16* Og = (z == 0) ? O0 : (z == 1) ? O1 : O2;

  const int tid = threadIdx.x, w = tid >> 6, lane = tid & 63;
  const int wr = w >> 2, wc = w & 3;
  const int fr = lane & 15, fq = lane >> 4;
  const int m0 = blockIdx.y * 256, n0 = blockIdx.x * 256;

  const int srow = lane >> 3;
  const int sunit = (lane & 7) ^ srow;
  const u16* gA = A  + (size_t)(m0 + w * 8 + srow) * HID + sunit * 8;
  const u16* gB = Bw + (size_t)(n0 + w * 8 + srow) * HID + sunit * 8;

  f32x4 acc[8][4] = {};

  // ---- prologue: stage K-tile 0 into buf 0 (order: A-lo, B, A-hi)
  {
    char* dA = smem + w * 1024;
    char* dB = smem + 65536 + w * 1024;
    async_ld16(gA,             dA);            // A h0 lo
    async_ld16(gA + 128 * HID, dA + 16384);    // A h1 lo
    async_ld16(gB,             dB);            // B h0 lo
    async_ld16(gB + 64 * HID,  dB + 8192);     // B h0 hi
    async_ld16(gB + 128 * HID, dB + 16384);    // B h1 lo
    async_ld16(gB + 192 * HID, dB + 24576);    // B h1 hi
    async_ld16(gA + 64 * HID,  dA + 8192);     // A h0 hi
    async_ld16(gA + 192 * HID, dA + 24576);    // A h1 hi
  }
  asm volatile("s_waitcnt vmcnt(2)" ::: "memory");   // A-lo + B done; A-hi may fly
  __builtin_amdgcn_s_barrier();

  bf16x8 af[4][2], bfr[4][2];
#pragma unroll 2
  for (int kt = 0; kt < HID / 64; ++kt) {
    const int p = kt & 1, q = p ^ 1;
    const int knext = (kt < HID / 64 - 1) ? (kt + 1) * 64 : kt * 64;  // clamp tail (harmless re-stage)
    const char* pA = smem + p * 32768 + wr * 16384;
    const char* pB = smem + 65536 + p * 32768 + (wc >> 1) * 16384;
    const u16* a    = gA + knext;
    const u16* bsrc = gB + knext;
    char* dA = smem + q * 32768 + w * 1024;
    char* dB = smem + 65536 + q * 32768 + w * 1024;

    // ============ P1: ds_read A i0-3 (8) + B j0-1 (4); stage A-lo(next)
#pragma unroll
    for (int i = 0; i < 4; ++i) {
      const int rl = i * 16 + fr;
      af[i][0] = *(const bf16x8*)(pA + rl * 128 + ((fq       ^ (rl & 7)) * 16));
      af[i][1] = *(const bf16x8*)(pA + rl * 128 + (((4 + fq) ^ (rl & 7)) * 16));
    }
#pragma unroll
    for (int j = 0; j < 2; ++j) {
      const int rbl = (wc & 1) * 64 + j * 16 + fr;
      bfr[j][0] = *(const bf16x8*)(pB + rbl * 128 + ((fq       ^ (rbl & 7)) * 16));
      bfr[j][1] = *(const bf16x8*)(pB + rbl * 128 + (((4 + fq) ^ (rbl & 7)) * 16));
    }
    async_ld16(a,             dA);
    async_ld16(a + 128 * HID, dA + 16384);
    __builtin_amdgcn_s_barrier();
    asm volatile("s_waitcnt lgkmcnt(0)" ::: "memory");
    __builtin_amdgcn_sched_barrier(0);
    __builtin_amdgcn_s_setprio(1);
#pragma unroll
    for (int i = 0; i < 4; ++i)
#pragma unroll
      for (int j = 0; j < 2; ++j) {
        acc[i][j] = __builtin_amdgcn_mfma_f32_16x16x32_bf16(bfr[j][0], af[i][0], acc[i][j], 0, 0, 0);
        acc[i][j] = __builtin_amdgcn_mfma_f32_16x16x32_bf16(bfr[j][1], af[i][1], acc[i][j], 0, 0, 0);
      }
    __builtin_amdgcn_s_setprio(0);
    __builtin_amdgcn_s_barrier();

    // ============ P2: ds_read B j2-3 (4); stage B-h0(next)
#pragma unroll
    for (int j = 2; j < 4; ++j) {
      const int rbl = (wc & 1) * 64 + j * 16 + fr;
      bfr[j][0] = *(const bf16x8*)(pB + rbl * 128 + ((fq       ^ (rbl & 7)) * 16));
      bfr[j][1] = *(const bf16x8*)(pB + rbl * 128 + (((4 + fq) ^ (rbl & 7)) * 16));
    }
    async_ld16(bsrc,            dB);
    async_ld16(bsrc + 64 * HID, dB + 8192);
    __builtin_amdgcn_s_barrier();
    asm volatile("s_waitcnt lgkmcnt(0)" ::: "memory");
    __builtin_amdgcn_sched_barrier(0);
    __builtin_amdgcn_s_setprio(1);
#pragma unroll
    for (int i = 0; i < 4; ++i)
#pragma unroll
      for (int j = 2; j < 4; ++j) {
        acc[i][j] = __builtin_amdgcn_mfma_f32_16x16x32_bf16(bfr[j][0], af[i][0], acc[i][j], 0, 0, 0);
        acc[i][j] = __builtin_amdgcn_mfma_f32_16x16x32_bf16(bfr[j][1], af[i][1], acc[i][j], 0, 0, 0);
      }
    __builtin_amdgcn_s_setprio(0);
    asm volatile("s_waitcnt vmcnt(4)" ::: "memory");   // A-hi(kt) landed (issued prev P4)
    __builtin_amdgcn_s_barrier();

    // ============ P3: ds_read A i4-7 (8, reuse af regs); stage B-h1(next)
#pragma unroll
    for (int i = 0; i < 4; ++i) {
      const int rl = (i + 4) * 16 + fr;
      af[i][0] = *(const bf16x8*)(pA + rl * 128 + ((fq       ^ (rl & 7)) * 16));
      af[i][1] = *(const bf16x8*)(pA + rl * 128 + (((4 + fq) ^ (rl & 7)) * 16));
    }
    async_ld16(bsrc + 128 * HID, dB + 16384);
    async_ld16(bsrc + 192 * HID, dB + 24576);
    __builtin_amdgcn_s_barrier();
    asm volatile("s_waitcnt lgkmcnt(0)" ::: "memory");
    __builtin_amdgcn_sched_barrier(0);
    __builtin_amdgcn_s_setprio(1);
#pragma unroll
    for (int i = 0; i < 4; ++i)
#pragma unroll
      for (int j = 0; j < 2; ++j) {
        acc[i + 4][j] = __builtin_amdgcn_mfma_f32_16x16x32_bf16(bfr[j][0], af[i][0], acc[i + 4][j], 0, 0, 0);
        acc[i + 4][j] = __builtin_amdgcn_mfma_f32_16x16x32_bf16(bfr[j][1], af[i][1], acc[i + 4][j], 0, 0, 0);
      }
    __builtin_amdgcn_s_setprio(0);
    __builtin_amdgcn_s_barrier();

    // ============ P4: stage A-hi(next); mfma i4-7 x j2-3 (all regs held)
    async_ld16(a + 64 * HID,  dA + 8192);
    async_ld16(a + 192 * HID, dA + 24576);
    __builtin_amdgcn_s_barrier();
    __builtin_amdgcn_s_setprio(1);
#pragma unroll
    for (int i = 0; i < 4; ++i)
#pragma unroll
      for (int j = 2; j < 4; ++j) {
        acc[i + 4][j] = __builtin_amdgcn_mfma_f32_16x16x32_bf16(bfr[j][0], af[i][0], acc[i + 4][j], 0, 0, 0);
        acc[i + 4][j] = __builtin_amdgcn_mfma_f32_16x16x32_bf16(bfr[j][1], af[i][1], acc[i + 4][j], 0, 0, 0);
      }
    __builtin_amdgcn_s_setprio(0);
    asm volatile("s_waitcnt vmcnt(2)" ::: "memory");   // A-lo + B of kt+1 landed
    __builtin_amdgcn_s_barrier();
  }
  asm volatile("s_waitcnt vmcnt(0)" ::: "memory");     // drain clamped tail stages
  __syncthreads();

  // ---------------- epilogue: C tile 256x256 bf16 staged in smem (pitch 512B, unit^(m&31))
  if (z < 2) {
#pragma unroll
    for (int i = 0; i < 8; ++i)
#pragma unroll
      for (int j = 0; j < 4; ++j) {
        const int m = wr * 128 + i * 16 + fr;
        const int nb = wc * 64 + j * 16 + fq * 4;
        union { bf16x4 v; uint2 u; } cv;
        cv.v = __builtin_convertvector(acc[i][j], bf16x4);
        *(uint2*)(smem + m * 512 + (((nb >> 3) ^ (m & 31)) * 16) + (nb & 7) * 2) = cv.u;
      }
    __syncthreads();
    // rope + coalesced store: 512 thr x 8 cols = 16 rows / iter
#pragma unroll
    for (int rr = 0; rr < 16; ++rr) {
      const int row = rr * 16 + (tid >> 5);
      const int nb = (tid & 31) * 8;
      const int i0 = nb & 63;
      const bf16x8 x  = *(const bf16x8*)(smem + row * 512 + (((nb >> 3) ^ (row & 31)) * 16));
      const bf16x8 xp = *(const bf16x8*)(smem + row * 512 + ((((nb ^ 64) >> 3) ^ (row & 31)) * 16));
      const int mg = m0 + row;
      const int s = mg & (SEQ - 1), b = mg >> 11;
      const float4 c0 = *(const float4*)(cosT + s * 64 + i0);
      const float4 c1 = *(const float4*)(cosT + s * 64 + i0 + 4);
      const float4 s0 = *(const float4*)(sinT + s * 64 + i0);
      const float4 s1 = *(const float4*)(sinT + s * 64 + i0 + 4);
      const float cs[8] = {c0.x, c0.y, c0.z, c0.w, c1.x, c1.y, c1.z, c1.w};
      const float sn[8] = {s0.x, s0.y, s0.z, s0.w, s1.x, s1.y, s1.z, s1.w};
      const float sgn = ((nb & 127) < 64) ? -1.f : 1.f;
      union { bf16x8 v; uint4 u; } o;
#pragma unroll
      for (int e = 0; e < 8; ++e)
        o.v[e] = (__bf16)((float)x[e] * cs[e] + sgn * (float)xp[e] * sn[e]);
      const int h = (n0 >> 7) + (nb >> 7);
      *(uint4*)(Og + (((size_t)(b * NH + h) * SEQ + s) << 7) + (nb & 127)) = o.u;
    }
  } else {
    // V: stage C^T [n=d][m=s] scalar, then coalesced Vt stores
#pragma unroll
    for (int i = 0; i < 8; ++i)
#pragma unroll
      for (int j = 0; j < 4; ++j)
#pragma unroll
        for (int r = 0; r < 4; ++r) {
          const int m = wr * 128 + i * 16 + fr;
          const int n = wc * 64 + j * 16 + fq * 4 + r;
          *(u16*)(smem + n * 512 + (((m >> 3) ^ (n & 31)) * 16) + (m & 7) * 2) = f2bf(acc[i][j][r]);
        }
    __syncthreads();
#pragma unroll
    for (int rr = 0; rr < 16; ++rr) {
      const int row = rr * 16 + (tid >> 5);     // local n (2 heads x 128 d)
      const int mb = (tid & 31) * 8;
      const uint4 v = *(const uint4*)(smem + row * 512 + (((mb >> 3) ^ (row & 31)) * 16));
      const int d = row & 127, h = (n0 >> 7) + (row >> 7);
      const int mg = m0 + mb;
      const int s = mg & (SEQ - 1), b = mg >> 11;
      *(uint4*)(Og + (((size_t)((b * NH + h) * HD + d)) << 11) + s) = v;
    }
  }
}

// ---------------------------------------------------------------- out-proj GEMM
// BM=128, BN=256, BK=64, 512 thr, per-wave 64x64. LDS 144 KiB triple-buffer.
// fp32 row-major out via LDS-staged coalesced float4 stores. Grid 8x32 = 256 blocks.
__global__ void __launch_bounds__(512, 2) gemm_out_kernel(
    const u16* __restrict__ A, const u16* __restrict__ Bw, float* __restrict__ O) {
  extern __shared__ __align__(16) char smem[];
  const int tid = threadIdx.x, w = tid >> 6, lane = tid & 63;
  const int wr = w >> 2, wc = w & 3;
  const int fr = lane & 15, fq = lane >> 4;
  const int m0 = blockIdx.y * 128, n0 = blockIdx.x * 256;

  constexpr int ABUF = 16384, BBUF = 32768;
  char* const sA0 = smem;
  char* const sB0 = smem + 3 * ABUF;

  const int srow = lane >> 3;
  const int sunit = (lane & 7) ^ srow;
  const u16* gA = A  + (size_t)(m0 + w * 8 + srow) * HID + sunit * 8;
  const u16* gB = Bw + (size_t)(n0 + w * 8 + srow) * HID + sunit * 8;

  f32x4 acc[4][4] = {};

  {
    char* dA = sA0 + w * 1024;
    char* dB = sB0 + w * 1024;
    async_ld16(gA,                 dA);
    async_ld16(gA + 64 * HID,      dA + 8192);
    async_ld16(gB,                 dB);
    async_ld16(gB + 64 * HID,      dB + 8192);
    async_ld16(gB + 128 * HID,     dB + 16384);
    async_ld16(gB + 192 * HID,     dB + 24576);
    async_ld16(gA + 64,                 dA + ABUF);
    async_ld16(gA + 64 + 64 * HID,      dA + ABUF + 8192);
    async_ld16(gB + 64,                 dB + BBUF);
    async_ld16(gB + 64 + 64 * HID,      dB + BBUF + 8192);
    async_ld16(gB + 64 + 128 * HID,     dB + BBUF + 16384);
    async_ld16(gB + 64 + 192 * HID,     dB + BBUF + 24576);
  }
  asm volatile("s_waitcnt vmcnt(6)" ::: "memory");
  __builtin_amdgcn_s_barrier();

  const char* prA = sA0;
  const char* prB = sB0;
  char* psA = sA0 + 2 * ABUF;
  char* psB = sB0 + 2 * BBUF;

  bf16x8 af[4][2], bfr[2][2];
  constexpr int NT = HID / 64;
#pragma unroll 1
  for (int kt = 0; kt < NT; ++kt) {
    const int kn = (kt + 2 < NT ? kt + 2 : NT - 1) * 64;
    const u16* a    = gA + kn;
    const u16* bsrc = gB + kn;
    char* dA = psA + w * 1024;
    char* dB = psB + w * 1024;

#pragma unroll
    for (int i = 0; i < 4; ++i) {
      const int rl = wr * 64 + i * 16 + fr;
      af[i][0] = *(const bf16x8*)(prA + rl * 128 + ((fq       ^ (rl & 7)) * 16));
      af[i][1] = *(const bf16x8*)(prA + rl * 128 + (((4 + fq) ^ (rl & 7)) * 16));
    }
#pragma unroll
    for (int j = 0; j < 2; ++j) {
      const int rb = wc * 64 + j * 16 + fr;
      bfr[j][0] = *(const bf16x8*)(prB + rb * 128 + ((fq       ^ (rb & 7)) * 16));
      bfr[j][1] = *(const bf16x8*)(prB + rb * 128 + (((4 + fq) ^ (rb & 7)) * 16));
    }
    async_ld16(a,            dA);
    async_ld16(a + 64 * HID, dA + 8192);
    async_ld16(bsrc,         dB);
    __builtin_amdgcn_s_barrier();
    asm volatile("s_waitcnt lgkmcnt(0)" ::: "memory");
    __builtin_amdgcn_sched_barrier(0);
    __builtin_amdgcn_s_setprio(1);
#pragma unroll
    for (int i = 0; i < 4; ++i)
#pragma unroll
      for (int j = 0; j < 2; ++j) {
        acc[i][j] = __builtin_amdgcn_mfma_f32_16x16x32_bf16(bfr[j][0], af[i][0], acc[i][j], 0, 0, 0);
        acc[i][j] = __builtin_amdgcn_mfma_f32_16x16x32_bf16(bfr[j][1], af[i][1], acc[i][j], 0, 0, 0);
      }
    __builtin_amdgcn_s_setprio(0);
    __builtin_amdgcn_s_barrier();

#pragma unroll
    for (int j = 0; j < 2; ++j) {
      const int rb = wc * 64 + (j + 2) * 16 + fr;
      bfr[j][0] = *(const bf16x8*)(prB + rb * 128 + ((fq       ^ (rb & 7)) * 16));
      bfr[j][1] = *(const bf16x8*)(prB + rb * 128 + (((4 + fq) ^ (rb & 7)) * 16));
    }
    async_ld16(bsrc + 64 * HID,  dB + 8192);
    async_ld16(bsrc + 128 * HID, dB + 16384);
    async_ld16(bsrc + 192 * HID, dB + 24576);
    __builtin_amdgcn_s_barrier();
    asm volatile("s_waitcnt lgkmcnt(0)" ::: "memory");
    __builtin_amdgcn_sched_barrier(0);
    __builtin_amdgcn_s_setprio(1);
#pragma unroll
    for (int i = 0; i < 4; ++i)
#pragma unroll
      for (int j = 0; j < 2; ++j) {
        acc[i][j + 2] = __builtin_amdgcn_mfma_f32_16x16x32_bf16(bfr[j][0], af[i][0], acc[i][j + 2], 0, 0, 0);
        acc[i][j + 2] = __builtin_amdgcn_mfma_f32_16x16x32_bf16(bfr[j][1], af[i][1], acc[i][j + 2], 0, 0, 0);
      }
    __builtin_amdgcn_s_setprio(0);
    asm volatile("s_waitcnt vmcnt(6)" ::: "memory");
    __builtin_amdgcn_s_barrier();

    prA += ABUF; if (prA == sA0 + 3 * ABUF) prA = sA0;
    prB += BBUF; if (prB == sB0 + 3 * BBUF) prB = sB0;
    psA += ABUF; if (psA == sA0 + 3 * ABUF) psA = sA0;
    psB += BBUF; if (psB == sB0 + 3 * BBUF) psB = sB0;
  }
  asm volatile("s_waitcnt vmcnt(0)" ::: "memory");
  __syncthreads();

  // stage fp32 C [128][256], pitch 1024B, 16B-unit swizzle ^(m&63); coalesced f32x4 stores
#pragma unroll
  for (int i = 0; i < 4; ++i)
#pragma unroll
    for (int j = 0; j < 4; ++j) {
      const int m = wr * 64 + i * 16 + fr;
      const int u = wc * 16 + j * 4 + fq;      // n/4
      *(f32x4*)(smem + m * 1024 + ((u ^ (m & 63)) * 16)) = acc[i][j];
    }
  __syncthreads();
#pragma unroll
  for (int rr = 0; rr < 16; ++rr) {
    const int row = rr * 8 + (tid >> 6);
    const int u = tid & 63;
    const f32x4 v = *(const f32x4*)(smem + row * 1024 + ((u ^ (row & 63)) * 16));
    *(f32x4*)(O + (size_t)(m0 + row) * HID + n0 + u * 4) = v;
  }
}

// ---------------------------------------------------------------- flash attention, 32x32x16 MFMA (verified R6)
// BlockQ=256 (8 waves x 32q, 512 thr), 64 keys/kt. S^T = K*Q^T; O^T = Vt*P^T.
// Grid 256 blocks = 1/CU, 2 waves/SIMD (the latency-hiding that R8's 4-wave x 64q
// variant destroyed — that REGRESSED ~+30 us; do not retry without occupancy).
// K/V double-buffered (2 x 32 KiB), counted vmcnt(4), raw barriers,
// XCD-aware block map, T13 defer-max.
__global__ void __launch_bounds__(512, 2) attn_kernel(const u16* __restrict__ Qg,
                                                      const u16* __restrict__ Kg,
                                                      const u16* __restrict__ Vtg,
                                                      u16* __restrict__ Ctx) {
  __shared__ __align__(16) char smem[65536];

  // XCD-aware map (id&7 assumed = XCD round-robin): each XCD runs 4 bh x 8 qt
  // concurrently -> its 4 MB K/V working set stays L2-resident.
  const int id = blockIdx.x;                 // 256 blocks
  const int s_ = id >> 3;                    // 0..31
  const int bh = (id & 7) + 8 * (s_ >> 3);   // 0..31
  const int qt = s_ & 7;                     // 8 q-tiles of 256 rows
  const int b = bh >> 4, h = bh & (NH - 1);
  const int tid = threadIdx.x, w = tid >> 6, lane = tid & 63;   // w 0..7
  const int ml = lane & 31, hi = lane >> 5;

  const u16* Kbase = Kg  + (size_t)bh * SEQ * HD;
  const u16* Vbase = Vtg + (size_t)bh * HD * SEQ;
  const u16* Qbase = Qg  + (size_t)bh * SEQ * HD;

  // ---- stage Q tile 256 x 128 (64 KB) across full smem, swizzled; 8 loads/wave
  {
    const int r4 = lane >> 4;
    const int up = lane & 15;
#pragma unroll
    for (int blk = 0; blk < 8; ++blk) {
      const int row = w * 32 + blk * 4 + r4;
      const int ul = up ^ (row & 15);
      async_ld16(Qbase + (size_t)(qt * 256 + row) * HD + ul * 8, smem + w * 8192 + blk * 1024);
    }
  }
  asm volatile("s_waitcnt vmcnt(0)" ::: "memory");
  __builtin_amdgcn_s_barrier();
  const int qrow = w * 32 + ml;
  bf16x8 qf[8];
#pragma unroll
  for (int kc = 0; kc < 8; ++kc)
    qf[kc] = *(const bf16x8*)(smem + qrow * 256 + (((kc * 2 + hi) ^ (qrow & 15)) * 16));
  asm volatile("s_waitcnt lgkmcnt(0)" ::: "memory");   // Q reads done before buf0 overwrite
  __builtin_amdgcn_sched_barrier(0);
  __builtin_amdgcn_s_barrier();

  const int r4 = lane >> 4, up16 = lane & 15;
  const int r8 = lane >> 3, up8 = lane & 7;

  // ---- prologue: stage kt=0 into buf0 (K at +0 [16K], V at +16384 [16K]); 4 loads/wave
  {
#pragma unroll
    for (int blk = 0; blk < 2; ++blk) {
      const int row = w * 8 + blk * 4 + r4;              // K rows 0..63
      const int ul = up16 ^ (row & 15);
      async_ld16(Kbase + (size_t)row * HD + ul * 8, smem + w * 2048 + blk * 1024);
    }
#pragma unroll
    for (int blk = 0; blk < 2; ++blk) {
      const int d = w * 16 + blk * 8 + r8;               // V d-rows 0..127
      const int ul = up8 ^ (d & 7);
      async_ld16(Vbase + (size_t)d * SEQ + ul * 8, smem + 16384 + w * 2048 + blk * 1024);
    }
  }

  f32x16 acco[4] = {};
  float m_run = -1e30f, l_run = 0.f;
  const float scale2 = (float)(1.4426950408889634 / 11.313708498984761);  // log2(e)/sqrt(128)
  constexpr int NT = SEQ / 64;

  for (int kt = 0; kt < NT; ++kt) {
    const char* bufR = smem + (kt & 1) * 32768;
    // issue stage(kt+1) into the other buffer, then counted wait for stage(kt).
    // ledger (per wave): 4 loads/tile, in-order retire -> vmcnt(4) == tile kt landed.
    if (kt + 1 < NT) {
      char* bufS = smem + ((kt + 1) & 1) * 32768;
      const int k0 = (kt + 1) * 64;
#pragma unroll
      for (int blk = 0; blk < 2; ++blk) {
        const int row = w * 8 + blk * 4 + r4;
        const int ul = up16 ^ (row & 15);
        async_ld16(Kbase + (size_t)(k0 + row) * HD + ul * 8, bufS + w * 2048 + blk * 1024);
      }
#pragma unroll
      for (int blk = 0; blk < 2; ++blk) {
        const int d = w * 16 + blk * 8 + r8;
        const int ul = up8 ^ (d & 7);
        async_ld16(Vbase + (size_t)d * SEQ + k0 + ul * 8, bufS + 16384 + w * 2048 + blk * 1024);
      }
      asm volatile("s_waitcnt vmcnt(4)" ::: "memory");
    } else {
      asm volatile("s_waitcnt vmcnt(0)" ::: "memory");
    }
    __builtin_amdgcn_s_barrier();

    f32x16 accs[2] = {};
    __builtin_amdgcn_s_setprio(1);
#pragma unroll
    for (int t = 0; t < 2; ++t) {
      const int row = t * 32 + ml;
#pragma unroll
      for (int kc = 0; kc < 8; ++kc) {
        const bf16x8 kf = *(const bf16x8*)(bufR + row * 256 + (((kc * 2 + hi) ^ (row & 15)) * 16));
        accs[t] = __builtin_amdgcn_mfma_f32_32x32x16_bf16(kf, qf[kc], accs[t], 0, 0, 0);
      }
    }
    __builtin_amdgcn_s_setprio(0);

    accs[0] *= scale2;
    accs[1] *= scale2;
    const f32x16 mm = __builtin_elementwise_max(accs[0], accs[1]);
    float mx = mm[0];
#pragma unroll
    for (int i = 1; i < 16; ++i) mx = fmaxf(mx, mm[i]);
    mx = fmaxf(mx, __shfl_xor(mx, 32));
    // T13 defer-max: only rescale when some row grew its max by > 8 (P bounded by 2^8)
    if (!__all(mx - m_run <= 8.f)) {
      const float mnew = fmaxf(m_run, mx);
      const float alpha = __builtin_amdgcn_exp2f(m_run - mnew);
      m_run = mnew;
      l_run *= alpha;
#pragma unroll
      for (int dt = 0; dt < 4; ++dt) acco[dt] *= alpha;
    }
    float rs = 0.f;
#pragma unroll
    for (int t = 0; t < 2; ++t)
#pragma unroll
      for (int i = 0; i < 16; ++i) {
        accs[t][i] = __builtin_amdgcn_exp2f(accs[t][i] - m_run);
        rs += accs[t][i];
      }
    rs += __shfl_xor(rs, 32);
    l_run += rs;

    u32 pk[2][4][2];
#pragma unroll
    for (int t = 0; t < 2; ++t)
#pragma unroll
      for (int g = 0; g < 4; ++g) {
        const f32x4 gv = {accs[t][4 * g], accs[t][4 * g + 1], accs[t][4 * g + 2], accs[t][4 * g + 3]};
        union { bf16x4 v; u32 u[2]; } cv; cv.v = __builtin_convertvector(gv, bf16x4);
        pk[t][g][0] = cv.u[0]; pk[t][g][1] = cv.u[1];
      }
    bf16x8 pf[4];
#pragma unroll
    for (int kc = 0; kc < 4; ++kc) {
      const int t = kc >> 1, g0 = (kc & 1) * 2;
      u32 a0 = pk[t][g0][0], a1 = pk[t][g0][1];
      u32 b0 = pk[t][g0 + 1][0], b1 = pk[t][g0 + 1][1];
      plswap(a0, b0); plswap(a1, b1);
      union { u32 u[4]; bf16x8 v; } fu;
      fu.u[0] = a0; fu.u[1] = a1; fu.u[2] = b0; fu.u[3] = b1;
      pf[kc] = fu.v;
    }

    __builtin_amdgcn_s_setprio(1);
#pragma unroll
    for (int dt = 0; dt < 4; ++dt) {
      const int d = dt * 32 + ml;
#pragma unroll
      for (int kc = 0; kc < 4; ++kc) {
        const bf16x8 vf = *(const bf16x8*)(bufR + 16384 + d * 128 + (((kc * 2 + hi) ^ (d & 7)) * 16));
        acco[dt] = __builtin_amdgcn_mfma_f32_32x32x16_bf16(vf, pf[kc], acco[dt], 0, 0, 0);
      }
    }
    __builtin_amdgcn_s_setprio(0);
    // all reads of bufR must COMPLETE before any wave's next-iter stage overwrites it
    asm volatile("s_waitcnt lgkmcnt(0)" ::: "memory");
    __builtin_amdgcn_sched_barrier(0);
    __builtin_amdgcn_s_barrier();
  }

  __syncthreads();
  const float rcp = 1.f / l_run;
  char* ep = smem + w * 8192;
#pragma unroll
  for (int dt = 0; dt < 4; ++dt) {
#pragma unroll
    for (int g = 0; g < 4; ++g) {
      const f32x4 gv = {acco[dt][4 * g] * rcp, acco[dt][4 * g + 1] * rcp,
                        acco[dt][4 * g + 2] * rcp, acco[dt][4 * g + 3] * rcp};
      union { bf16x4 v; uint2 u2; } cv; cv.v = __builtin_convertvector(gv, bf16x4);
      const int ul = dt * 4 + g;
      *(uint2*)(ep + ml * 256 + ((ul ^ (ml & 15)) * 16) + hi * 8) = cv.u2;
    }
  }
  __syncthreads();
#pragma unroll
  for (int rr = 0; rr < 8; ++rr) {
    const int idr = rr * 64 + lane;
    const int qv = idr >> 4, ul = idr & 15;
    const uint4 v = *(const uint4*)(ep + qv * 256 + ((ul ^ (qv & 15)) * 16));
    *(uint4*)(Ctx + (size_t)(b * SEQ + qt * 256 + w * 32 + qv) * HID + h * HD + ul * 8) = v;
  }
}

// ---------------------------------------------------------------- launcher
extern "C" void kernel_launch(void* const* d_in, const int* in_sizes, int n_in,
                              void* d_out, int out_size, void* d_ws, size_t ws_size,
                              hipStream_t stream) {
  (void)in_sizes; (void)n_in; (void)out_size; (void)ws_size;
  const float* X  = (const float*)d_in[0];
  const float* Wq = (const float*)d_in[1];
  const float* Wk = (const float*)d_in[2];
  const float* Wv = (const float*)d_in[3];
  const float* Wo = (const float*)d_in[4];
  float* out = (float*)d_out;
  char* ws = (char*)d_ws;
  const size_t MB = 1024 * 1024;
  u16* Xb  = (u16*)(ws + 0 * MB);
  u16* Wqb = (u16*)(ws + 16 * MB);
  u16* Wkb = (u16*)(ws + 24 * MB);
  u16* Wvb = (u16*)(ws + 32 * MB);
  u16* Wob = (u16*)(ws + 40 * MB);
  u16* Qb  = (u16*)(ws + 48 * MB);
  u16* Kb  = (u16*)(ws + 64 * MB);
  u16* Vtb = (u16*)(ws + 80 * MB);   // [B,NH,HD,S] — written directly by gemm_qkv256 z=2
  // rope tables live in the Ctx region: read only by the QKV gemm, dead before attn writes Ctx
  float* cosT = (float*)(ws + 96 * MB);
  float* sinT = cosT + SEQ * 64;
  u16* Ctx = (u16*)(ws + 96 * MB);

  static bool attr_set = false;
  if (!attr_set) {
    hipFuncSetAttribute(reinterpret_cast<const void*>(&gemm_qkv256_kernel),
                        hipFuncAttributeMaxDynamicSharedMemorySize, 131072);
    hipFuncSetAttribute(reinterpret_cast<const void*>(&gemm_out_kernel),
                        hipFuncAttributeMaxDynamicSharedMemorySize, 147456);
    attr_set = true;
  }

  cast5_kernel<<<dim3(24704), 256, 0, stream>>>(X, Wq, Wk, Wv, Wo,
                                                Xb, Wqb, Wkb, Wvb, Wob, cosT, sinT);
  gemm_qkv256_kernel<<<dim3(HID / 256, (BATCH * SEQ) / 256, 3), 512, 131072, stream>>>(
      Xb, Wqb, Wkb, Wvb, Qb, Kb, Vtb, cosT, sinT);
  // attn: 256 blocks (8 q-tiles x 32 bh) = exactly 1 block/CU, 512 thr (8 waves x 32 q)
  attn_kernel<<<dim3((SEQ / 256) * BATCH * NH), 512, 0, stream>>>(Qb, Kb, Vtb, Ctx);
  gemm_out_kernel<<<dim3(HID / 256, (BATCH * SEQ) / 128), 512, 147456, stream>>>(
      Ctx, Wob, out);
}

// Round 10
// 353.628 us; speedup vs baseline: 1.1120x; 1.0122x over previous
//
#include <hip/hip_runtime.h>
#include <stdint.h>

#define SEQ   2048
#define HID   2048
#define NH    16
#define HD    128
#define BATCH 2

typedef unsigned short u16;
typedef unsigned int   u32;
typedef __attribute__((ext_vector_type(8)))  __bf16 bf16x8;
typedef __attribute__((ext_vector_type(4)))  __bf16 bf16x4;
typedef __attribute__((ext_vector_type(4)))  float  f32x4;
typedef __attribute__((ext_vector_type(16))) float  f32x16;

__device__ __forceinline__ u16 f2bf(float f) {
  union { float f; unsigned int u; } c; c.f = f;
  unsigned int u = c.u;
  return (u16)((u + 0x7fffu + ((u >> 16) & 1u)) >> 16);   // RNE
}

// async global->LDS, 16B/lane. HW writes wave-uniform LDS base + lane*16.
__device__ __forceinline__ void async_ld16(const void* g, void* s) {
  using gptr_t = const __attribute__((address_space(1))) char*;
  using sptr_t = __attribute__((address_space(3))) char*;
  __builtin_amdgcn_global_load_lds((gptr_t)(uintptr_t)g, (sptr_t)(uintptr_t)s, 16, 0, 0);
}

#if __has_builtin(__builtin_amdgcn_permlane32_swap)
__device__ __forceinline__ void plswap(u32& a, u32& b) {
  typedef __attribute__((ext_vector_type(2))) unsigned int u32x2;
  u32x2 r = __builtin_amdgcn_permlane32_swap(a, b, false, false);
  a = r[0]; b = r[1];
}
#else
__device__ __forceinline__ void plswap(u32& a, u32& b) {
  const int hi = (threadIdx.x & 63) >> 5;
  u32 sa = (u32)__shfl_xor((int)a, 32);
  u32 sb = (u32)__shfl_xor((int)b, 32);
  u32 na = hi ? sb : a;
  u32 nb = hi ? b  : sa;
  a = na; b = nb;
}
#endif

// ---------------------------------------------------------------- fused casts + rope tables
// exact 1-D grid: [0,8192) X; [8192,24576) Wq/Wk/Wv/Wo (4096 each); [24576,24704) rope.
__global__ void __launch_bounds__(256) cast5_kernel(
    const float* __restrict__ X,  const float* __restrict__ Wq,
    const float* __restrict__ Wk, const float* __restrict__ Wv,
    const float* __restrict__ Wo,
    u16* __restrict__ Xb, u16* __restrict__ Wqb, u16* __restrict__ Wkb,
    u16* __restrict__ Wvb, u16* __restrict__ Wob,
    float* __restrict__ cosT, float* __restrict__ sinT) {
  const int id = blockIdx.x;
  const int tid = threadIdx.x;
  if (id >= 24576) {
    const int idx = (id - 24576) * 256 + tid;          // < 32768 exact
    const int s = idx >> 4, i0 = (idx & 15) * 4;
    float4 c, sn;
    float* cp = &c.x; float* sp = &sn.x;
#pragma unroll
    for (int e = 0; e < 4; ++e) {
      const float inv = exp2f(-(float)(i0 + e) * 0.20762050593045702f);  // log2(1e4)/64
      const float ang = (float)s * inv;
      cp[e] = cosf(ang); sp[e] = sinf(ang);
    }
    ((float4*)cosT)[idx] = c;
    ((float4*)sinT)[idx] = sn;
    return;
  }
  const float* in; u16* out; int idx;
  if (id < 8192) { in = X; out = Xb; idx = id * 256 + tid; }
  else {
    const int seg = (id - 8192) >> 12;                 // 0..3
    idx = ((id - 8192) & 4095) * 256 + tid;
    in  = (seg == 0) ? Wq  : (seg == 1) ? Wk  : (seg == 2) ? Wv  : Wo;
    out = (seg == 0) ? Wqb : (seg == 1) ? Wkb : (seg == 2) ? Wvb : Wob;
  }
  const float4 v = ((const float4*)in)[idx];
  union { u16 us[4]; uint2 u2; } o;
  o.us[0] = f2bf(v.x); o.us[1] = f2bf(v.y); o.us[2] = f2bf(v.z); o.us[3] = f2bf(v.w);
  ((uint2*)out)[idx] = o.u2;
}

// ---------------------------------------------------------------- 256x256 4-phase QKV GEMM (verified R1/R3/R5/R6/R9)
// C[m,n] = sum_k A[m,k]*W[n,k]; M=4096, N=K=2048, 3 weights via blockIdx.z.
// BM=BN=256, BK=64, 8 waves (2M x 4N), per-wave 128x64. LDS 128 KiB dbuf.
// kt+1 staged into OPPOSITE-parity buffer; counted vmcnt(4)/vmcnt(2) once each
// per K-tile (never 0 in loop); max 10 loads outstanding.
// SCHEDULE IS A LOCAL OPTIMUM — do not mutate:
//  [R4: 16-outstanding same-parity kt+2 restage REGRESSED 121->155 us]
//  [R8: bunching all 4 B-loads into P2 REGRESSED 120->125.5 us]
// acc holds C^T per frag (operand-swapped): col=m (lane&15), row=n (fq*4+r).
__global__ void __launch_bounds__(512, 2) gemm_qkv256_kernel(
    const u16* __restrict__ A,
    const u16* __restrict__ B0, const u16* __restrict__ B1, const u16* __restrict__ B2,
    u16* __restrict__ O0, u16* __restrict__ O1, u16* __restrict__ O2,
    const float* __restrict__ cosT, const float* __restrict__ sinT) {
  extern __shared__ __align__(16) char smem[];
  const int z = blockIdx.z;
  const u16* Bw = (z == 0) ? B0 : (z == 1) ? B1 : B2;
  u16* Og = (z == 0) ? O0 : (z == 1) ? O1 : O2;

  const int tid = threadIdx.x, w = tid >> 6, lane = tid & 63;
  const int wr = w >> 2, wc = w & 3;
  const int fr = lane & 15, fq = lane >> 4;
  const int m0 = blockIdx.y * 256, n0 = blockIdx.x * 256;

  const int srow = lane >> 3;
  const int sunit = (lane & 7) ^ srow;
  const u16* gA = A  + (size_t)(m0 + w * 8 + srow) * HID + sunit * 8;
  const u16* gB = Bw + (size_t)(n0 + w * 8 + srow) * HID + sunit * 8;

  f32x4 acc[8][4] = {};

  // ---- prologue: stage K-tile 0 into buf 0 (order: A-lo, B, A-hi)
  {
    char* dA = smem + w * 1024;
    char* dB = smem + 65536 + w * 1024;
    async_ld16(gA,             dA);            // A h0 lo
    async_ld16(gA + 128 * HID, dA + 16384);    // A h1 lo
    async_ld16(gB,             dB);            // B h0 lo
    async_ld16(gB + 64 * HID,  dB + 8192);     // B h0 hi
    async_ld16(gB + 128 * HID, dB + 16384);    // B h1 lo
    async_ld16(gB + 192 * HID, dB + 24576);    // B h1 hi
    async_ld16(gA + 64 * HID,  dA + 8192);     // A h0 hi
    async_ld16(gA + 192 * HID, dA + 24576);    // A h1 hi
  }
  asm volatile("s_waitcnt vmcnt(2)" ::: "memory");   // A-lo + B done; A-hi may fly
  __builtin_amdgcn_s_barrier();

  bf16x8 af[4][2], bfr[4][2];
#pragma unroll 2
  for (int kt = 0; kt < HID / 64; ++kt) {
    const int p = kt & 1, q = p ^ 1;
    const int knext = (kt < HID / 64 - 1) ? (kt + 1) * 64 : kt * 64;  // clamp tail (harmless re-stage)
    const char* pA = smem + p * 32768 + wr * 16384;
    const char* pB = smem + 65536 + p * 32768 + (wc >> 1) * 16384;
    const u16* a    = gA + knext;
    const u16* bsrc = gB + knext;
    char* dA = smem + q * 32768 + w * 1024;
    char* dB = smem + 65536 + q * 32768 + w * 1024;

    // ============ P1: ds_read A i0-3 (8) + B j0-1 (4); stage A-lo(next)
#pragma unroll
    for (int i = 0; i < 4; ++i) {
      const int rl = i * 16 + fr;
      af[i][0] = *(const bf16x8*)(pA + rl * 128 + ((fq       ^ (rl & 7)) * 16));
      af[i][1] = *(const bf16x8*)(pA + rl * 128 + (((4 + fq) ^ (rl & 7)) * 16));
    }
#pragma unroll
    for (int j = 0; j < 2; ++j) {
      const int rbl = (wc & 1) * 64 + j * 16 + fr;
      bfr[j][0] = *(const bf16x8*)(pB + rbl * 128 + ((fq       ^ (rbl & 7)) * 16));
      bfr[j][1] = *(const bf16x8*)(pB + rbl * 128 + (((4 + fq) ^ (rbl & 7)) * 16));
    }
    async_ld16(a,             dA);
    async_ld16(a + 128 * HID, dA + 16384);
    __builtin_amdgcn_s_barrier();
    asm volatile("s_waitcnt lgkmcnt(0)" ::: "memory");
    __builtin_amdgcn_sched_barrier(0);
    __builtin_amdgcn_s_setprio(1);
#pragma unroll
    for (int i = 0; i < 4; ++i)
#pragma unroll
      for (int j = 0; j < 2; ++j) {
        acc[i][j] = __builtin_amdgcn_mfma_f32_16x16x32_bf16(bfr[j][0], af[i][0], acc[i][j], 0, 0, 0);
        acc[i][j] = __builtin_amdgcn_mfma_f32_16x16x32_bf16(bfr[j][1], af[i][1], acc[i][j], 0, 0, 0);
      }
    __builtin_amdgcn_s_setprio(0);
    __builtin_amdgcn_s_barrier();

    // ============ P2: ds_read B j2-3 (4); stage B-h0(next)
#pragma unroll
    for (int j = 2; j < 4; ++j) {
      const int rbl = (wc & 1) * 64 + j * 16 + fr;
      bfr[j][0] = *(const bf16x8*)(pB + rbl * 128 + ((fq       ^ (rbl & 7)) * 16));
      bfr[j][1] = *(const bf16x8*)(pB + rbl * 128 + (((4 + fq) ^ (rbl & 7)) * 16));
    }
    async_ld16(bsrc,            dB);
    async_ld16(bsrc + 64 * HID, dB + 8192);
    __builtin_amdgcn_s_barrier();
    asm volatile("s_waitcnt lgkmcnt(0)" ::: "memory");
    __builtin_amdgcn_sched_barrier(0);
    __builtin_amdgcn_s_setprio(1);
#pragma unroll
    for (int i = 0; i < 4; ++i)
#pragma unroll
      for (int j = 2; j < 4; ++j) {
        acc[i][j] = __builtin_amdgcn_mfma_f32_16x16x32_bf16(bfr[j][0], af[i][0], acc[i][j], 0, 0, 0);
        acc[i][j] = __builtin_amdgcn_mfma_f32_16x16x32_bf16(bfr[j][1], af[i][1], acc[i][j], 0, 0, 0);
      }
    __builtin_amdgcn_s_setprio(0);
    asm volatile("s_waitcnt vmcnt(4)" ::: "memory");   // A-hi(kt) landed (issued prev P4)
    __builtin_amdgcn_s_barrier();

    // ============ P3: ds_read A i4-7 (8, reuse af regs); stage B-h1(next)
#pragma unroll
    for (int i = 0; i < 4; ++i) {
      const int rl = (i + 4) * 16 + fr;
      af[i][0] = *(const bf16x8*)(pA + rl * 128 + ((fq       ^ (rl & 7)) * 16));
      af[i][1] = *(const bf16x8*)(pA + rl * 128 + (((4 + fq) ^ (rl & 7)) * 16));
    }
    async_ld16(bsrc + 128 * HID, dB + 16384);
    async_ld16(bsrc + 192 * HID, dB + 24576);
    __builtin_amdgcn_s_barrier();
    asm volatile("s_waitcnt lgkmcnt(0)" ::: "memory");
    __builtin_amdgcn_sched_barrier(0);
    __builtin_amdgcn_s_setprio(1);
#pragma unroll
    for (int i = 0; i < 4; ++i)
#pragma unroll
      for (int j = 0; j < 2; ++j) {
        acc[i + 4][j] = __builtin_amdgcn_mfma_f32_16x16x32_bf16(bfr[j][0], af[i][0], acc[i + 4][j], 0, 0, 0);
        acc[i + 4][j] = __builtin_amdgcn_mfma_f32_16x16x32_bf16(bfr[j][1], af[i][1], acc[i + 4][j], 0, 0, 0);
      }
    __builtin_amdgcn_s_setprio(0);
    __builtin_amdgcn_s_barrier();

    // ============ P4: stage A-hi(next); mfma i4-7 x j2-3 (all regs held)
    async_ld16(a + 64 * HID,  dA + 8192);
    async_ld16(a + 192 * HID, dA + 24576);
    __builtin_amdgcn_s_barrier();
    __builtin_amdgcn_s_setprio(1);
#pragma unroll
    for (int i = 0; i < 4; ++i)
#pragma unroll
      for (int j = 2; j < 4; ++j) {
        acc[i + 4][j] = __builtin_amdgcn_mfma_f32_16x16x32_bf16(bfr[j][0], af[i][0], acc[i + 4][j], 0, 0, 0);
        acc[i + 4][j] = __builtin_amdgcn_mfma_f32_16x16x32_bf16(bfr[j][1], af[i][1], acc[i + 4][j], 0, 0, 0);
      }
    __builtin_amdgcn_s_setprio(0);
    asm volatile("s_waitcnt vmcnt(2)" ::: "memory");   // A-lo + B of kt+1 landed
    __builtin_amdgcn_s_barrier();
  }
  asm volatile("s_waitcnt vmcnt(0)" ::: "memory");     // drain clamped tail stages
  __syncthreads();

  // ---------------- epilogue: C tile 256x256 bf16 staged in smem (pitch 512B, unit^(m&31))
  if (z < 2) {
#pragma unroll
    for (int i = 0; i < 8; ++i)
#pragma unroll
      for (int j = 0; j < 4; ++j) {
        const int m = wr * 128 + i * 16 + fr;
        const int nb = wc * 64 + j * 16 + fq * 4;
        union { bf16x4 v; uint2 u; } cv;
        cv.v = __builtin_convertvector(acc[i][j], bf16x4);
        *(uint2*)(smem + m * 512 + (((nb >> 3) ^ (m & 31)) * 16) + (nb & 7) * 2) = cv.u;
      }
    __syncthreads();
    // rope + coalesced store: 512 thr x 8 cols = 16 rows / iter
#pragma unroll
    for (int rr = 0; rr < 16; ++rr) {
      const int row = rr * 16 + (tid >> 5);
      const int nb = (tid & 31) * 8;
      const int i0 = nb & 63;
      const bf16x8 x  = *(const bf16x8*)(smem + row * 512 + (((nb >> 3) ^ (row & 31)) * 16));
      const bf16x8 xp = *(const bf16x8*)(smem + row * 512 + ((((nb ^ 64) >> 3) ^ (row & 31)) * 16));
      const int mg = m0 + row;
      const int s = mg & (SEQ - 1), b = mg >> 11;
      const float4 c0 = *(const float4*)(cosT + s * 64 + i0);
      const float4 c1 = *(const float4*)(cosT + s * 64 + i0 + 4);
      const float4 s0 = *(const float4*)(sinT + s * 64 + i0);
      const float4 s1 = *(const float4*)(sinT + s * 64 + i0 + 4);
      const float cs[8] = {c0.x, c0.y, c0.z, c0.w, c1.x, c1.y, c1.z, c1.w};
      const float sn[8] = {s0.x, s0.y, s0.z, s0.w, s1.x, s1.y, s1.z, s1.w};
      const float sgn = ((nb & 127) < 64) ? -1.f : 1.f;
      union { bf16x8 v; uint4 u; } o;
#pragma unroll
      for (int e = 0; e < 8; ++e)
        o.v[e] = (__bf16)((float)x[e] * cs[e] + sgn * (float)xp[e] * sn[e]);
      const int h = (n0 >> 7) + (nb >> 7);
      *(uint4*)(Og + (((size_t)(b * NH + h) * SEQ + s) << 7) + (nb & 127)) = o.u;
    }
  } else {
    // V: stage C^T [n=d][m=s] scalar, then coalesced Vt stores
#pragma unroll
    for (int i = 0; i < 8; ++i)
#pragma unroll
      for (int j = 0; j < 4; ++j)
#pragma unroll
        for (int r = 0; r < 4; ++r) {
          const int m = wr * 128 + i * 16 + fr;
          const int n = wc * 64 + j * 16 + fq * 4 + r;
          *(u16*)(smem + n * 512 + (((m >> 3) ^ (n & 31)) * 16) + (m & 7) * 2) = f2bf(acc[i][j][r]);
        }
    __syncthreads();
#pragma unroll
    for (int rr = 0; rr < 16; ++rr) {
      const int row = rr * 16 + (tid >> 5);     // local n (2 heads x 128 d)
      const int mb = (tid & 31) * 8;
      const uint4 v = *(const uint4*)(smem + row * 512 + (((mb >> 3) ^ (row & 31)) * 16));
      const int d = row & 127, h = (n0 >> 7) + (row >> 7);
      const int mg = m0 + mb;
      const int s = mg & (SEQ - 1), b = mg >> 11;
      *(uint4*)(Og + (((size_t)((b * NH + h) * HD + d)) << 11) + s) = v;
    }
  }
}

// ---------------------------------------------------------------- out-proj GEMM
// BM=128, BN=256, BK=64, 512 thr, per-wave 64x64. LDS 144 KiB triple-buffer.
// fp32 row-major out via LDS-staged coalesced float4 stores. Grid 8x32 = 256 blocks.
__global__ void __launch_bounds__(512, 2) gemm_out_kernel(
    const u16* __restrict__ A, const u16* __restrict__ Bw, float* __restrict__ O) {
  extern __shared__ __align__(16) char smem[];
  const int tid = threadIdx.x, w = tid >> 6, lane = tid & 63;
  const int wr = w >> 2, wc = w & 3;
  const int fr = lane & 15, fq = lane >> 4;
  const int m0 = blockIdx.y * 128, n0 = blockIdx.x * 256;

  constexpr int ABUF = 16384, BBUF = 32768;
  char* const sA0 = smem;
  char* const sB0 = smem + 3 * ABUF;

  const int srow = lane >> 3;
  const int sunit = (lane & 7) ^ srow;
  const u16* gA = A  + (size_t)(m0 + w * 8 + srow) * HID + sunit * 8;
  const u16* gB = Bw + (size_t)(n0 + w * 8 + srow) * HID + sunit * 8;

  f32x4 acc[4][4] = {};

  {
    char* dA = sA0 + w * 1024;
    char* dB = sB0 + w * 1024;
    async_ld16(gA,                 dA);
    async_ld16(gA + 64 * HID,      dA + 8192);
    async_ld16(gB,                 dB);
    async_ld16(gB + 64 * HID,      dB + 8192);
    async_ld16(gB + 128 * HID,     dB + 16384);
    async_ld16(gB + 192 * HID,     dB + 24576);
    async_ld16(gA + 64,                 dA + ABUF);
    async_ld16(gA + 64 + 64 * HID,      dA + ABUF + 8192);
    async_ld16(gB + 64,                 dB + BBUF);
    async_ld16(gB + 64 + 64 * HID,      dB + BBUF + 8192);
    async_ld16(gB + 64 + 128 * HID,     dB + BBUF + 16384);
    async_ld16(gB + 64 + 192 * HID,     dB + BBUF + 24576);
  }
  asm volatile("s_waitcnt vmcnt(6)" ::: "memory");
  __builtin_amdgcn_s_barrier();

  const char* prA = sA0;
  const char* prB = sB0;
  char* psA = sA0 + 2 * ABUF;
  char* psB = sB0 + 2 * BBUF;

  bf16x8 af[4][2], bfr[2][2];
  constexpr int NT = HID / 64;
#pragma unroll 1
  for (int kt = 0; kt < NT; ++kt) {
    const int kn = (kt + 2 < NT ? kt + 2 : NT - 1) * 64;
    const u16* a    = gA + kn;
    const u16* bsrc = gB + kn;
    char* dA = psA + w * 1024;
    char* dB = psB + w * 1024;

#pragma unroll
    for (int i = 0; i < 4; ++i) {
      const int rl = wr * 64 + i * 16 + fr;
      af[i][0] = *(const bf16x8*)(prA + rl * 128 + ((fq       ^ (rl & 7)) * 16));
      af[i][1] = *(const bf16x8*)(prA + rl * 128 + (((4 + fq) ^ (rl & 7)) * 16));
    }
#pragma unroll
    for (int j = 0; j < 2; ++j) {
      const int rb = wc * 64 + j * 16 + fr;
      bfr[j][0] = *(const bf16x8*)(prB + rb * 128 + ((fq       ^ (rb & 7)) * 16));
      bfr[j][1] = *(const bf16x8*)(prB + rb * 128 + (((4 + fq) ^ (rb & 7)) * 16));
    }
    async_ld16(a,            dA);
    async_ld16(a + 64 * HID, dA + 8192);
    async_ld16(bsrc,         dB);
    __builtin_amdgcn_s_barrier();
    asm volatile("s_waitcnt lgkmcnt(0)" ::: "memory");
    __builtin_amdgcn_sched_barrier(0);
    __builtin_amdgcn_s_setprio(1);
#pragma unroll
    for (int i = 0; i < 4; ++i)
#pragma unroll
      for (int j = 0; j < 2; ++j) {
        acc[i][j] = __builtin_amdgcn_mfma_f32_16x16x32_bf16(bfr[j][0], af[i][0], acc[i][j], 0, 0, 0);
        acc[i][j] = __builtin_amdgcn_mfma_f32_16x16x32_bf16(bfr[j][1], af[i][1], acc[i][j], 0, 0, 0);
      }
    __builtin_amdgcn_s_setprio(0);
    __builtin_amdgcn_s_barrier();

#pragma unroll
    for (int j = 0; j < 2; ++j) {
      const int rb = wc * 64 + (j + 2) * 16 + fr;
      bfr[j][0] = *(const bf16x8*)(prB + rb * 128 + ((fq       ^ (rb & 7)) * 16));
      bfr[j][1] = *(const bf16x8*)(prB + rb * 128 + (((4 + fq) ^ (rb & 7)) * 16));
    }
    async_ld16(bsrc + 64 * HID,  dB + 8192);
    async_ld16(bsrc + 128 * HID, dB + 16384);
    async_ld16(bsrc + 192 * HID, dB + 24576);
    __builtin_amdgcn_s_barrier();
    asm volatile("s_waitcnt lgkmcnt(0)" ::: "memory");
    __builtin_amdgcn_sched_barrier(0);
    __builtin_amdgcn_s_setprio(1);
#pragma unroll
    for (int i = 0; i < 4; ++i)
#pragma unroll
      for (int j = 0; j < 2; ++j) {
        acc[i][j + 2] = __builtin_amdgcn_mfma_f32_16x16x32_bf16(bfr[j][0], af[i][0], acc[i][j + 2], 0, 0, 0);
        acc[i][j + 2] = __builtin_amdgcn_mfma_f32_16x16x32_bf16(bfr[j][1], af[i][1], acc[i][j + 2], 0, 0, 0);
      }
    __builtin_amdgcn_s_setprio(0);
    asm volatile("s_waitcnt vmcnt(6)" ::: "memory");
    __builtin_amdgcn_s_barrier();

    prA += ABUF; if (prA == sA0 + 3 * ABUF) prA = sA0;
    prB += BBUF; if (prB == sB0 + 3 * BBUF) prB = sB0;
    psA += ABUF; if (psA == sA0 + 3 * ABUF) psA = sA0;
    psB += BBUF; if (psB == sB0 + 3 * BBUF) psB = sB0;
  }
  asm volatile("s_waitcnt vmcnt(0)" ::: "memory");
  __syncthreads();

  // stage fp32 C [128][256], pitch 1024B, 16B-unit swizzle ^(m&63); coalesced f32x4 stores
#pragma unroll
  for (int i = 0; i < 4; ++i)
#pragma unroll
    for (int j = 0; j < 4; ++j) {
      const int m = wr * 64 + i * 16 + fr;
      const int u = wc * 16 + j * 4 + fq;      // n/4
      *(f32x4*)(smem + m * 1024 + ((u ^ (m & 63)) * 16)) = acc[i][j];
    }
  __syncthreads();
#pragma unroll
  for (int rr = 0; rr < 16; ++rr) {
    const int row = rr * 8 + (tid >> 6);
    const int u = tid & 63;
    const f32x4 v = *(const f32x4*)(smem + row * 1024 + ((u ^ (row & 63)) * 16));
    *(f32x4*)(O + (size_t)(m0 + row) * HID + n0 + u * 4) = v;
  }
}

// ---------------------------------------------------------------- flash attention, 32x32x16 MFMA
// BlockQ=256 (8 waves x 32q, 512 thr), KVBLK=128 keys/tile (was 64 in R6).
// S^T = K*Q^T; O^T = Vt*P^T. Grid 256 blocks = 1/CU, 2 waves/SIMD.
// CHANGE vs R6: per-tile fixed costs (2 barriers, 1 vmcnt wait, 1 softmax
// max/alpha pass, 1 stage burst) now amortize over 128 keys instead of 64;
// per-key LDS/MFMA/exp work identical. Wave shape untouched (R8 lesson).
// LDS 128 KiB dynamic: dbuf x {K 128x256B = 32K, V 128d x 256B = 32K}.
// Ledger unchanged: 8 loads/wave/tile, vmcnt(8) retires tile kt. NT=16.
// VGPR risk: accs[4]+acco[4]+qf[8] ~ 250; launch_bounds(512,2) caps at 256.
__global__ void __launch_bounds__(512, 2) attn_kernel(const u16* __restrict__ Qg,
                                                      const u16* __restrict__ Kg,
                                                      const u16* __restrict__ Vtg,
                                                      u16* __restrict__ Ctx) {
  extern __shared__ __align__(16) char smem[];   // 131072 B

  // XCD-aware map (id&7 assumed = XCD round-robin): each XCD runs 4 bh x 8 qt
  // concurrently -> its 4 MB K/V working set stays L2-resident.
  const int id = blockIdx.x;                 // 256 blocks
  const int s_ = id >> 3;                    // 0..31
  const int bh = (id & 7) + 8 * (s_ >> 3);   // 0..31
  const int qt = s_ & 7;                     // 8 q-tiles of 256 rows
  const int b = bh >> 4, h = bh & (NH - 1);
  const int tid = threadIdx.x, w = tid >> 6, lane = tid & 63;   // w 0..7
  const int ml = lane & 31, hi = lane >> 5;

  const u16* Kbase = Kg  + (size_t)bh * SEQ * HD;
  const u16* Vbase = Vtg + (size_t)bh * HD * SEQ;
  const u16* Qbase = Qg  + (size_t)bh * SEQ * HD;

  // ---- stage Q tile 256 x 128 (64 KB) into smem[0:64K], swizzled; 8 loads/wave
  {
    const int r4 = lane >> 4;
    const int up = lane & 15;
#pragma unroll
    for (int blk = 0; blk < 8; ++blk) {
      const int row = w * 32 + blk * 4 + r4;
      const int ul = up ^ (row & 15);
      async_ld16(Qbase + (size_t)(qt * 256 + row) * HD + ul * 8, smem + w * 8192 + blk * 1024);
    }
  }
  asm volatile("s_waitcnt vmcnt(0)" ::: "memory");
  __builtin_amdgcn_s_barrier();
  const int qrow = w * 32 + ml;
  bf16x8 qf[8];
#pragma unroll
  for (int kc = 0; kc < 8; ++kc)
    qf[kc] = *(const bf16x8*)(smem + qrow * 256 + (((kc * 2 + hi) ^ (qrow & 15)) * 16));
  asm volatile("s_waitcnt lgkmcnt(0)" ::: "memory");   // Q reads done before buf0 overwrite
  __builtin_amdgcn_sched_barrier(0);
  __builtin_amdgcn_s_barrier();

  const int r4 = lane >> 4, up16 = lane & 15;

  // ---- prologue: stage kt=0 into buf0 (K at +0 [32K], V at +32768 [32K]); 8 loads/wave
  {
#pragma unroll
    for (int blk = 0; blk < 4; ++blk) {
      const int row = w * 16 + blk * 4 + r4;             // K rows 0..127
      const int ul = up16 ^ (row & 15);
      async_ld16(Kbase + (size_t)row * HD + ul * 8, smem + w * 4096 + blk * 1024);
    }
#pragma unroll
    for (int blk = 0; blk < 4; ++blk) {
      const int d = w * 16 + blk * 4 + r4;               // V d-rows 0..127, 128 k/row
      const int ul = up16 ^ (d & 15);
      async_ld16(Vbase + (size_t)d * SEQ + ul * 8, smem + 32768 + w * 4096 + blk * 1024);
    }
  }

  f32x16 acco[4] = {};
  float m_run = -1e30f, l_run = 0.f;
  const float scale2 = (float)(1.4426950408889634 / 11.313708498984761);  // log2(e)/sqrt(128)
  constexpr int NT = SEQ / 128;   // 16 tiles of 128 keys

  for (int kt = 0; kt < NT; ++kt) {
    const char* bufR = smem + (kt & 1) * 65536;
    // issue stage(kt+1) into the other buffer, then counted wait for stage(kt).
    // ledger (per wave): 8 loads/tile, in-order retire -> vmcnt(8) == tile kt landed.
    if (kt + 1 < NT) {
      char* bufS = smem + ((kt + 1) & 1) * 65536;
      const int k0 = (kt + 1) * 128;
#pragma unroll
      for (int blk = 0; blk < 4; ++blk) {
        const int row = w * 16 + blk * 4 + r4;
        const int ul = up16 ^ (row & 15);
        async_ld16(Kbase + (size_t)(k0 + row) * HD + ul * 8, bufS + w * 4096 + blk * 1024);
      }
#pragma unroll
      for (int blk = 0; blk < 4; ++blk) {
        const int d = w * 16 + blk * 4 + r4;
        const int ul = up16 ^ (d & 15);
        async_ld16(Vbase + (size_t)d * SEQ + k0 + ul * 8, bufS + 32768 + w * 4096 + blk * 1024);
      }
      asm volatile("s_waitcnt vmcnt(8)" ::: "memory");
    } else {
      asm volatile("s_waitcnt vmcnt(0)" ::: "memory");
    }
    __builtin_amdgcn_s_barrier();

    // ---- QK^T: 4 x 32-key blocks, 32 MFMA
    f32x16 accs[4] = {};
    __builtin_amdgcn_s_setprio(1);
#pragma unroll
    for (int t = 0; t < 4; ++t) {
      const int row = t * 32 + ml;
#pragma unroll
      for (int kc = 0; kc < 8; ++kc) {
        const bf16x8 kf = *(const bf16x8*)(bufR + row * 256 + (((kc * 2 + hi) ^ (row & 15)) * 16));
        accs[t] = __builtin_amdgcn_mfma_f32_32x32x16_bf16(kf, qf[kc], accs[t], 0, 0, 0);
      }
    }
    __builtin_amdgcn_s_setprio(0);

#pragma unroll
    for (int t = 0; t < 4; ++t) accs[t] *= scale2;
    f32x16 mm = __builtin_elementwise_max(accs[0], accs[1]);
    mm = __builtin_elementwise_max(mm, accs[2]);
    mm = __builtin_elementwise_max(mm, accs[3]);
    float mx = mm[0];
#pragma unroll
    for (int i = 1; i < 16; ++i) mx = fmaxf(mx, mm[i]);
    mx = fmaxf(mx, __shfl_xor(mx, 32));
    // T13 defer-max: only rescale when some row grew its max by > 8 (P bounded by 2^8)
    if (!__all(mx - m_run <= 8.f)) {
      const float mnew = fmaxf(m_run, mx);
      const float alpha = __builtin_amdgcn_exp2f(m_run - mnew);
      m_run = mnew;
      l_run *= alpha;
#pragma unroll
      for (int dt = 0; dt < 4; ++dt) acco[dt] *= alpha;
    }
    float rs = 0.f;
#pragma unroll
    for (int t = 0; t < 4; ++t)
#pragma unroll
      for (int i = 0; i < 16; ++i) {
        accs[t][i] = __builtin_amdgcn_exp2f(accs[t][i] - m_run);
        rs += accs[t][i];
      }
    rs += __shfl_xor(rs, 32);
    l_run += rs;

    // ---- pack P -> bf16 fragments: pf[kc] = P for keys kc*16..kc*16+15
    u32 pk[4][4][2];
#pragma unroll
    for (int t = 0; t < 4; ++t)
#pragma unroll
      for (int g = 0; g < 4; ++g) {
        const f32x4 gv = {accs[t][4 * g], accs[t][4 * g + 1], accs[t][4 * g + 2], accs[t][4 * g + 3]};
        union { bf16x4 v; u32 u[2]; } cv; cv.v = __builtin_convertvector(gv, bf16x4);
        pk[t][g][0] = cv.u[0]; pk[t][g][1] = cv.u[1];
      }
    bf16x8 pf[8];
#pragma unroll
    for (int kc = 0; kc < 8; ++kc) {
      const int t = kc >> 1, g0 = (kc & 1) * 2;
      u32 a0 = pk[t][g0][0], a1 = pk[t][g0][1];
      u32 b0 = pk[t][g0 + 1][0], b1 = pk[t][g0 + 1][1];
      plswap(a0, b0); plswap(a1, b1);
      union { u32 u[4]; bf16x8 v; } fu;
      fu.u[0] = a0; fu.u[1] = a1; fu.u[2] = b0; fu.u[3] = b1;
      pf[kc] = fu.v;
    }

    // ---- PV: 32 MFMA (k-dim 128)
    __builtin_amdgcn_s_setprio(1);
#pragma unroll
    for (int dt = 0; dt < 4; ++dt) {
      const int d = dt * 32 + ml;
#pragma unroll
      for (int kc = 0; kc < 8; ++kc) {
        const bf16x8 vf = *(const bf16x8*)(bufR + 32768 + d * 256 + (((kc * 2 + hi) ^ (d & 15)) * 16));
        acco[dt] = __builtin_amdgcn_mfma_f32_32x32x16_bf16(vf, pf[kc], acco[dt], 0, 0, 0);
      }
    }
    __builtin_amdgcn_s_setprio(0);
    // all reads of bufR must COMPLETE before any wave's next-iter stage overwrites it
    asm volatile("s_waitcnt lgkmcnt(0)" ::: "memory");
    __builtin_amdgcn_sched_barrier(0);
    __builtin_amdgcn_s_barrier();
  }

  __syncthreads();
  const float rcp = 1.f / l_run;
  char* ep = smem + w * 8192;
#pragma unroll
  for (int dt = 0; dt < 4; ++dt) {
#pragma unroll
    for (int g = 0; g < 4; ++g) {
      const f32x4 gv = {acco[dt][4 * g] * rcp, acco[dt][4 * g + 1] * rcp,
                        acco[dt][4 * g + 2] * rcp, acco[dt][4 * g + 3] * rcp};
      union { bf16x4 v; uint2 u2; } cv; cv.v = __builtin_convertvector(gv, bf16x4);
      const int ul = dt * 4 + g;
      *(uint2*)(ep + ml * 256 + ((ul ^ (ml & 15)) * 16) + hi * 8) = cv.u2;
    }
  }
  __syncthreads();
#pragma unroll
  for (int rr = 0; rr < 8; ++rr) {
    const int idr = rr * 64 + lane;
    const int qv = idr >> 4, ul = idr & 15;
    const uint4 v = *(const uint4*)(ep + qv * 256 + ((ul ^ (qv & 15)) * 16));
    *(uint4*)(Ctx + (size_t)(b * SEQ + qt * 256 + w * 32 + qv) * HID + h * HD + ul * 8) = v;
  }
}

// ---------------------------------------------------------------- launcher
extern "C" void kernel_launch(void* const* d_in, const int* in_sizes, int n_in,
                              void* d_out, int out_size, void* d_ws, size_t ws_size,
                              hipStream_t stream) {
  (void)in_sizes; (void)n_in; (void)out_size; (void)ws_size;
  const float* X  = (const float*)d_in[0];
  const float* Wq = (const float*)d_in[1];
  const float* Wk = (const float*)d_in[2];
  const float* Wv = (const float*)d_in[3];
  const float* Wo = (const float*)d_in[4];
  float* out = (float*)d_out;
  char* ws = (char*)d_ws;
  const size_t MB = 1024 * 1024;
  u16* Xb  = (u16*)(ws + 0 * MB);
  u16* Wqb = (u16*)(ws + 16 * MB);
  u16* Wkb = (u16*)(ws + 24 * MB);
  u16* Wvb = (u16*)(ws + 32 * MB);
  u16* Wob = (u16*)(ws + 40 * MB);
  u16* Qb  = (u16*)(ws + 48 * MB);
  u16* Kb  = (u16*)(ws + 64 * MB);
  u16* Vtb = (u16*)(ws + 80 * MB);   // [B,NH,HD,S] — written directly by gemm_qkv256 z=2
  // rope tables live in the Ctx region: read only by the QKV gemm, dead before attn writes Ctx
  float* cosT = (float*)(ws + 96 * MB);
  float* sinT = cosT + SEQ * 64;
  u16* Ctx = (u16*)(ws + 96 * MB);

  static bool attr_set = false;
  if (!attr_set) {
    hipFuncSetAttribute(reinterpret_cast<const void*>(&gemm_qkv256_kernel),
                        hipFuncAttributeMaxDynamicSharedMemorySize, 131072);
    hipFuncSetAttribute(reinterpret_cast<const void*>(&gemm_out_kernel),
                        hipFuncAttributeMaxDynamicSharedMemorySize, 147456);
    hipFuncSetAttribute(reinterpret_cast<const void*>(&attn_kernel),
                        hipFuncAttributeMaxDynamicSharedMemorySize, 131072);
    attr_set = true;
  }

  cast5_kernel<<<dim3(24704), 256, 0, stream>>>(X, Wq, Wk, Wv, Wo,
                                                Xb, Wqb, Wkb, Wvb, Wob, cosT, sinT);
  gemm_qkv256_kernel<<<dim3(HID / 256, (BATCH * SEQ) / 256, 3), 512, 131072, stream>>>(
      Xb, Wqb, Wkb, Wvb, Qb, Kb, Vtb, cosT, sinT);
  // attn: 256 blocks (8 q-tiles x 32 bh) = exactly 1 block/CU, 512 thr (8 waves x 32 q)
  attn_kernel<<<dim3((SEQ / 256) * BATCH * NH), 512, 131072, stream>>>(Qb, Kb, Vtb, Ctx);
  gemm_out_kernel<<<dim3(HID / 256, (BATCH * SEQ) / 128), 512, 147456, stream>>>(
      Ctx, Wob, out);
}